// Round 12
// baseline (173.693 us; speedup 1.0000x reference)
//
#include <hip/hip_runtime.h>
#include <hip/hip_bf16.h>

// Sizes
// B=8, N=1024, S=16, C=3, H=8, DIM=768, HD=96, SCALE=96^-0.5, BN_EPS=1e-3
//
// Algebraic restructuring (R5): out = BN(P@W_re)@V collapses to
//   out[n][d] = sum_m P[n][m] * M2[m][d] + cv[d]
//   M2[m][d]  = sum_p W_re[m][p] * G[p] * V[p][d]      (12.9 GF, batched bh)
//   cv[d]     = sum_p Cc[p] * V[p][d]
// R12: conv rebuilt — 81 weights hoisted to VGPRs (were re-read from LDS
//      324x/thread), x staged as 18x18 zero-halo float4 tile (9 unconditional
//      ds_read_b128 per token instead of 27 scalar reads + divergent bounds).

typedef __attribute__((ext_vector_type(4))) float f32x4;
typedef __bf16 __attribute__((ext_vector_type(8))) bf16x8;
typedef unsigned short u16x8 __attribute__((ext_vector_type(8)));

__device__ __forceinline__ unsigned short f2bf(float x){
  unsigned u = __builtin_bit_cast(unsigned, x);
  u += 0x7fffu + ((u >> 16) & 1u);          // round-to-nearest-even
  return (unsigned short)(u >> 16);
}

__device__ __forceinline__ float bf2f(unsigned short u){
  unsigned v = (unsigned)u << 16;
  return __builtin_bit_cast(float, v);
}

__device__ __forceinline__ f32x4 mfma16(bf16x8 a, bf16x8 b, f32x4 c){
  return __builtin_amdgcn_mfma_f32_16x16x32_bf16(a, b, c, 0, 0, 0);
}

__device__ __forceinline__ bf16x8 ld8(const unsigned short* p){
  return *reinterpret_cast<const bf16x8*>(p);
}

// ---------------------------------------------------------------------------
// Prep: Wre_rm[m][p] = bf16(w_re[m][p]) (coalesced cast);
//       G[p] = gamma*rsqrt(var+eps); Cc=(b_re-mean)*G+beta; CoverG=Cc/G
// ---------------------------------------------------------------------------
__global__ void prep_kernel(const float* __restrict__ w_re, const float* __restrict__ b_re,
                            const float* __restrict__ gma, const float* __restrict__ beta,
                            const float* __restrict__ mean, const float* __restrict__ var,
                            unsigned short* __restrict__ Wre_rm,
                            float* __restrict__ G, float* __restrict__ Cc,
                            float* __restrict__ CoverG)
{
  int idx = blockIdx.x * 256 + threadIdx.x;
  if (idx < 1024*1024){
    Wre_rm[idx] = f2bf(w_re[idx]);
  } else if (idx < 1024*1024 + 1024){
    int p = idx - 1024*1024;
    float g = gma[p] * rsqrtf(var[p] + 1e-3f);
    float cc = (b_re[p] - mean[p]) * g + beta[p];
    G[p] = g;
    Cc[p] = cc;
    CoverG[p] = cc / g;
  }
}

// ---------------------------------------------------------------------------
// Wpt[o][i] = bf16(w_proj[i][o]) via LDS 64x64 tiles (coalesced both sides)
// ---------------------------------------------------------------------------
__global__ __launch_bounds__(256) void wpt_kernel(const float* __restrict__ wp,
                                                  unsigned short* __restrict__ Wpt)
{
  __shared__ float t[64][65];
  const int i0 = blockIdx.x * 64, o0 = blockIdx.y * 64;
  const int r = threadIdx.x >> 6;        // 0..3
  const int c = threadIdx.x & 63;        // 0..63
#pragma unroll
  for (int rep = 0; rep < 16; ++rep){
    int row = rep*4 + r;
    t[row][c] = wp[(size_t)(i0 + row)*768 + o0 + c];
  }
  __syncthreads();
#pragma unroll
  for (int rep = 0; rep < 16; ++rep){
    int orow = rep*4 + r;
    Wpt[(size_t)(o0 + orow)*768 + i0 + c] = f2bf(t[c][orow]);
  }
}

// ---------------------------------------------------------------------------
// Conv 3x3 SAME (R12); 4 tokens/block, pixel-per-thread.
// Weights register-resident (81 VGPR); x staged as 18x18 zero-halo float4
// tile -> 9 unconditional ds_read_b128 + 81 FMA per token per thread.
// qh/kh/vh all [B,H,N,96] row-major; vh pre-scaled by G[n].
// ---------------------------------------------------------------------------
__global__ __launch_bounds__(256) void conv_kernel(
    const float* __restrict__ q, const float* __restrict__ k,
    const float* __restrict__ v,
    const float* __restrict__ wq, const float* __restrict__ wk,
    const float* __restrict__ wv,
    const float* __restrict__ G,
    unsigned short* __restrict__ qh, unsigned short* __restrict__ kh,
    unsigned short* __restrict__ vh)
{
  const int tb = blockIdx.x;         // 0..2047 (4 tokens each)
  const int which = blockIdx.y;      // 0=q 1=k 2=v
  const float* x = (which == 0) ? q : (which == 1) ? k : v;
  const float* w = (which == 0) ? wq : (which == 1) ? wk : wv;
  unsigned short* dst = (which == 0) ? qh : (which == 1) ? kh : vh;

  __shared__ __align__(16) float xs4[4][324][4];   // 18x18 halo, float4 pixels: 20736 B
  __shared__ float wsm[81];
  const int tid = threadIdx.x;

  // zero-fill (halo), then interior fill after a barrier (avoids write race)
  for (int i = tid; i < 4*324; i += 256){
    xs4[i >> 9 ? i/324 : i/324][i%324][0] = 0.f;   // (kept simple below)
  }
  // simpler: linear clear of all 4*324*4 floats
  {
    float* base = &xs4[0][0][0];
    for (int i = tid; i < 4*324*4; i += 256) base[i] = 0.f;
  }
  if (tid < 81) wsm[tid] = w[tid];
  __syncthreads();

  // interior fill: x[tb*4*768 + i], i = tk*768 + (r*16+c)*3 + ci
  for (int i = tid; i < 4*768; i += 256){
    int tk = i / 768, p = i - tk*768;
    int pix = p / 3, ci = p - pix*3;
    int r = pix >> 4, c = pix & 15;
    xs4[tk][(r + 1)*18 + (c + 1)][ci] = x[(size_t)tb*4*768 + i];
  }
  __syncthreads();

  // hoist weights into registers (static indices -> stays in VGPRs)
  float wreg[81];
#pragma unroll
  for (int i = 0; i < 81; ++i) wreg[i] = wsm[i];

  const int pix = tid;               // 0..255
  const int c = pix & 15, r = pix >> 4;

#pragma unroll
  for (int tk = 0; tk < 4; ++tk){
    float a0 = 0.f, a1 = 0.f, a2 = 0.f;
#pragma unroll
    for (int dr = 0; dr < 3; ++dr){
#pragma unroll
      for (int dc = 0; dc < 3; ++dc){
        const f32x4 xv = *reinterpret_cast<const f32x4*>(&xs4[tk][(r + dr)*18 + (c + dc)][0]);
        const int wb = (dr*3 + dc)*9;
        a0 += xv[0]*wreg[wb+0] + xv[1]*wreg[wb+3] + xv[2]*wreg[wb+6];
        a1 += xv[0]*wreg[wb+1] + xv[1]*wreg[wb+4] + xv[2]*wreg[wb+7];
        a2 += xv[0]*wreg[wb+2] + xv[1]*wreg[wb+5] + xv[2]*wreg[wb+8];
      }
    }
    const int token = tb*4 + tk;
    const int b = token >> 10, n = token & 1023;
    const float gs = (which == 2) ? G[n] : 1.f;
    float av[3] = {a0*gs, a1*gs, a2*gs};
#pragma unroll
    for (int co = 0; co < 3; ++co){
      int f = pix*3 + co;                   // head boundary (96) never splits a thread
      int h = f / 96, d = f - h*96;
      dst[((size_t)(b*8 + h)*1024 + n)*96 + d] = f2bf(av[co]);
    }
  }
}

// ---------------------------------------------------------------------------
// Transpose vh[bh][n][96] -> vtg[bh][d][n] via LDS tile, coalesced both sides.
// Grid (8 n-chunks, 64 bh).
// ---------------------------------------------------------------------------
__global__ __launch_bounds__(256) void vt_kernel(const unsigned short* __restrict__ vh,
                                                 unsigned short* __restrict__ vtg)
{
  __shared__ unsigned short t[96*136];       // row d: stride 136 (272 B, 16B-aligned, odd*16B)
  const int chunk = blockIdx.x;              // 0..7
  const int bh = blockIdx.y;                 // 0..63
  const int n0 = chunk*128;
  const int tid = threadIdx.x;

  const unsigned short* src = vh + ((size_t)bh*1024 + n0)*96;
#pragma unroll
  for (int it = 0; it < 6; ++it){
    int idx = it*256 + tid;                  // 0..1535
    int row = idx / 12, v = idx - row*12;    // row 0..127, v 0..11
    u16x8 xv = *reinterpret_cast<const u16x8*>(src + row*96 + v*8);
#pragma unroll
    for (int j = 0; j < 8; ++j) t[(v*8 + j)*136 + row] = xv[j];
  }
  __syncthreads();

  unsigned short* dstp = vtg + (size_t)bh*96*1024 + n0;
#pragma unroll
  for (int it = 0; it < 6; ++it){
    int idx = it*256 + tid;                  // 0..1535
    int d = idx >> 4, ch = idx & 15;         // d 0..95, ch 0..15
    u16x8 xv = *reinterpret_cast<const u16x8*>(&t[d*136 + ch*8]);
    *reinterpret_cast<u16x8*>(dstp + (size_t)d*1024 + ch*8) = xv;
  }
}

// ---------------------------------------------------------------------------
// cv[bh][d] = sum_p CoverG[p] * vtg[bh][d][p]   (= sum_p Cc[p]*V[p][d])
// Grid 512: block = (bh, 12-d chunk); each wave handles 3 d's.
// ---------------------------------------------------------------------------
__global__ __launch_bounds__(256) void cv_kernel(const unsigned short* __restrict__ vtg,
                                                 const float* __restrict__ CoverG,
                                                 float* __restrict__ cv)
{
  const int id = blockIdx.x;
  const int bh = id >> 3;
  const int d0 = (id & 7) * 12;
  const int tid = threadIdx.x;
  const int w = tid >> 6, lane = tid & 63;
  const unsigned short* vb = vtg + (size_t)bh * 96 * 1024;

#pragma unroll
  for (int dd = 0; dd < 3; ++dd){
    int d = d0 + w*3 + dd;
    const unsigned short* row = vb + (size_t)d * 1024;
    float s = 0.f;
#pragma unroll
    for (int j = 0; j < 16; ++j){
      int p = j*64 + lane;
      s += CoverG[p] * bf2f(row[p]);
    }
#pragma unroll
    for (int off = 1; off < 64; off <<= 1) s += __shfl_xor(s, off);
    if (lane == 0) cv[(size_t)bh*96 + d] = s;
  }
}

// ---------------------------------------------------------------------------
// M2t[bh][d][m] = sum_p Wre_rm[m][p] * vtg[bh][d][p]   (K = 1024 over p)
// R11: block-staged double-buffered W-tile (128x32) + V-tile (96x32);
// 4 waves x 32 m-rows; 12 MFMA/wave-iter; one barrier/iter.
// ---------------------------------------------------------------------------
__global__ __launch_bounds__(256, 2) void m2_kernel(
    const unsigned short* __restrict__ Wre_rm, const unsigned short* __restrict__ vtg,
    unsigned short* __restrict__ M2t)
{
  constexpr int WST = 40;   // W-tile row stride (u16): 128 x 40
  constexpr int VST = 40;   // V-tile row stride (u16): 96 x 40
  __shared__ __align__(16) unsigned short Wst[2][128*WST];   // 20480 B
  __shared__ __align__(16) unsigned short Vst[2][96*VST];    // 15360 B -> 35840 B

  const int id = blockIdx.x;             // 0..511
  const int xcd = id & 7, slot = id >> 3;
  const int mtile = slot & 7;            // 0..7
  const int bh = xcd + ((slot >> 3) << 3);
  const int tid = threadIdx.x;
  const int w = tid >> 6, lane = tid & 63, lh = lane >> 4, lm = lane & 15;
  const int m0 = mtile*128;              // block's m-base
  const int mw = w*32;                   // wave's m offset in tile

  const unsigned short* vb = vtg + (size_t)bh * 96 * 1024;
  const unsigned short* Wb = Wre_rm + (size_t)m0 * 1024;

  const int cr = tid >> 2, cc0 = (tid & 3)*8;
  const bool has3 = (tid < 128);

  f32x4 acc[2][6];
#pragma unroll
  for (int rt = 0; rt < 2; ++rt)
#pragma unroll
    for (int dt = 0; dt < 6; ++dt)
      acc[rt][dt] = f32x4{0.f, 0.f, 0.f, 0.f};

  // --- prologue: stage p-tile 0 into buffer 0 ---
  u16x8 g0, g1, g2, g3;
  g0 = *reinterpret_cast<const u16x8*>(Wb + (size_t)cr*1024 + cc0);
  g1 = *reinterpret_cast<const u16x8*>(Wb + (size_t)(64 + cr)*1024 + cc0);
  g2 = *reinterpret_cast<const u16x8*>(vb + (size_t)cr*1024 + cc0);
  if (has3) g3 = *reinterpret_cast<const u16x8*>(vb + (size_t)(64 + cr)*1024 + cc0);
  *reinterpret_cast<u16x8*>(&Wst[0][cr*WST + cc0]) = g0;
  *reinterpret_cast<u16x8*>(&Wst[0][(64 + cr)*WST + cc0]) = g1;
  *reinterpret_cast<u16x8*>(&Vst[0][cr*VST + cc0]) = g2;
  if (has3) *reinterpret_cast<u16x8*>(&Vst[0][(64 + cr)*VST + cc0]) = g3;
  __syncthreads();

  for (int ks = 0; ks < 32; ++ks){
    const int cur = ks & 1;

    if (ks < 31){
      const int p0 = (ks+1)*32;
      g0 = *reinterpret_cast<const u16x8*>(Wb + (size_t)cr*1024 + p0 + cc0);
      g1 = *reinterpret_cast<const u16x8*>(Wb + (size_t)(64 + cr)*1024 + p0 + cc0);
      g2 = *reinterpret_cast<const u16x8*>(vb + (size_t)cr*1024 + p0 + cc0);
      if (has3) g3 = *reinterpret_cast<const u16x8*>(vb + (size_t)(64 + cr)*1024 + p0 + cc0);
    }

    const unsigned short* Wc = &Wst[cur][0];
    const unsigned short* Vc = &Vst[cur][0];
    bf16x8 aW0 = ld8(Wc + (mw + lm)*WST + lh*8);
    bf16x8 aW1 = ld8(Wc + (mw + 16 + lm)*WST + lh*8);
#pragma unroll
    for (int dt = 0; dt < 6; ++dt){
      bf16x8 bV = ld8(Vc + (dt*16 + lm)*VST + lh*8);
      acc[0][dt] = mfma16(aW0, bV, acc[0][dt]);
      acc[1][dt] = mfma16(aW1, bV, acc[1][dt]);
    }

    if (ks < 31){
      const int nxt = cur ^ 1;
      *reinterpret_cast<u16x8*>(&Wst[nxt][cr*WST + cc0]) = g0;
      *reinterpret_cast<u16x8*>(&Wst[nxt][(64 + cr)*WST + cc0]) = g1;
      *reinterpret_cast<u16x8*>(&Vst[nxt][cr*VST + cc0]) = g2;
      if (has3) *reinterpret_cast<u16x8*>(&Vst[nxt][(64 + cr)*VST + cc0]) = g3;
    }
    __syncthreads();
  }

#pragma unroll
  for (int rt = 0; rt < 2; ++rt)
#pragma unroll
    for (int dt = 0; dt < 6; ++dt)
#pragma unroll
      for (int rg = 0; rg < 4; ++rg){
        int m = m0 + mw + rt*16 + lh*4 + rg;
        int d = dt*16 + lm;
        M2t[((size_t)bh*96 + d)*1024 + m] = f2bf(acc[rt][dt][rg]);
      }
}

// ---------------------------------------------------------------------------
// Fused attention (R9): block-staged K/M2 tiles, double-buffered.
// 256 thr = 4 waves; block owns 128 q-rows of one bh; wave w: 32 rows.
// ---------------------------------------------------------------------------
__global__ __launch_bounds__(256, 2) void attn_kernel(
    const unsigned short* __restrict__ qh, const unsigned short* __restrict__ kh,
    const unsigned short* __restrict__ M2t, const float* __restrict__ cv,
    unsigned short* __restrict__ xh)
{
  constexpr int KST = 104;   // K-tile row stride (u16): 32 x 104
  constexpr int MST = 40;    // M-tile row stride (u16): 96 x 40
  constexpr int PST = 40;    // P stage row stride (u16): 32 x 40 per wave
  __shared__ __align__(16) unsigned short Kst[2][32*KST];    // 13312 B
  __shared__ __align__(16) unsigned short Mst[2][96*MST];    // 15360 B
  __shared__ __align__(16) unsigned short Pst[2][4][32*PST]; // 20480 B -> total 49152 B

  const int id = blockIdx.x;             // 0..511
  const int xcd = id & 7, slot = id >> 3;
  const int chunk = slot & 7;            // 128-row chunk
  const int bh = xcd + ((slot >> 3) << 3);
  const int tid = threadIdx.x;
  const int w = tid >> 6;                // 0..3
  const int lane = tid & 63;
  const int lh = lane >> 4;              // 0..3
  const int lm = lane & 15;              // 0..15
  const int q0 = chunk*128 + w*32;       // this wave's 32 q-rows

  const unsigned short* Qb = qh + (size_t)bh * 1024 * 96;
  const unsigned short* Kb = kh + (size_t)bh * 1024 * 96;
  const unsigned short* Mb = M2t + (size_t)bh * 96 * 1024;

  const int kr0 = tid/12,  kc0 = (tid%12)*8;
  const bool c1K = (tid < 128);
  const int t1 = tid + 256;
  const int kr1 = c1K ? t1/12 : 0,  kc1 = c1K ? (t1%12)*8 : 0;
  const int md1 = c1K ? 0 : (tid-128)>>2, mc1 = c1K ? 0 : ((tid-128)&3)*8;
  const int md2 = (tid+128)>>2, mc2 = ((tid+128)&3)*8;

  bf16x8 aq[2][3];
#pragma unroll
  for (int rt = 0; rt < 2; ++rt)
#pragma unroll
    for (int kq = 0; kq < 3; ++kq)
      aq[rt][kq] = ld8(Qb + (size_t)(q0 + rt*16 + lm)*96 + kq*32 + lh*8);

  f32x4 out[2][6];
#pragma unroll
  for (int rt = 0; rt < 2; ++rt)
#pragma unroll
    for (int dt = 0; dt < 6; ++dt) out[rt][dt] = f32x4{0.f, 0.f, 0.f, 0.f};
  f32x4 ssum[2] = {f32x4{0.f,0.f,0.f,0.f}, f32x4{0.f,0.f,0.f,0.f}};

  const float SCALE = 0.10206207261596577f;

  u16x8 g0, g1, g2;
  {
    g0 = *reinterpret_cast<const u16x8*>(Kb + (size_t)kr0*96 + kc0);
    g1 = c1K ? *reinterpret_cast<const u16x8*>(Kb + (size_t)kr1*96 + kc1)
             : *reinterpret_cast<const u16x8*>(Mb + (size_t)md1*1024 + mc1);
    g2 = *reinterpret_cast<const u16x8*>(Mb + (size_t)md2*1024 + mc2);
    *reinterpret_cast<u16x8*>(&Kst[0][kr0*KST + kc0]) = g0;
    if (c1K) *reinterpret_cast<u16x8*>(&Kst[0][kr1*KST + kc1]) = g1;
    else     *reinterpret_cast<u16x8*>(&Mst[0][md1*MST + mc1]) = g1;
    *reinterpret_cast<u16x8*>(&Mst[0][md2*MST + mc2]) = g2;
  }
  __syncthreads();

  for (int kt = 0; kt < 32; ++kt){
    const int cur = kt & 1;

    if (kt < 31){
      const int kb = (kt+1)*32;
      g0 = *reinterpret_cast<const u16x8*>(Kb + (size_t)(kb + kr0)*96 + kc0);
      g1 = c1K ? *reinterpret_cast<const u16x8*>(Kb + (size_t)(kb + kr1)*96 + kc1)
               : *reinterpret_cast<const u16x8*>(Mb + (size_t)md1*1024 + kb + mc1);
      g2 = *reinterpret_cast<const u16x8*>(Mb + (size_t)md2*1024 + kb + mc2);
    }

    const unsigned short* Kc = &Kst[cur][0];
    f32x4 sacc[2][2];
    sacc[0][0] = f32x4{0.f,0.f,0.f,0.f}; sacc[0][1] = f32x4{0.f,0.f,0.f,0.f};
    sacc[1][0] = f32x4{0.f,0.f,0.f,0.f}; sacc[1][1] = f32x4{0.f,0.f,0.f,0.f};
#pragma unroll
    for (int kq = 0; kq < 3; ++kq){
      bf16x8 bk0 = ld8(Kc + lm*KST        + kq*32 + lh*8);
      bf16x8 bk1 = ld8(Kc + (16 + lm)*KST + kq*32 + lh*8);
      sacc[0][0] = mfma16(aq[0][kq], bk0, sacc[0][0]);
      sacc[0][1] = mfma16(aq[0][kq], bk1, sacc[0][1]);
      sacc[1][0] = mfma16(aq[1][kq], bk0, sacc[1][0]);
      sacc[1][1] = mfma16(aq[1][kq], bk1, sacc[1][1]);
    }

    unsigned short* Pc = &Pst[cur][w][0];
#pragma unroll
    for (int rt = 0; rt < 2; ++rt)
#pragma unroll
      for (int nt = 0; nt < 2; ++nt)
#pragma unroll
        for (int rg = 0; rg < 4; ++rg){
          float e = __expf(sacc[rt][nt][rg] * SCALE);
          ssum[rt][rg] += e;
          Pc[(rt*16 + lh*4 + rg)*PST + nt*16 + lm] = f2bf(e);
        }

    bf16x8 ap0 = ld8(Pc + lm*PST        + lh*8);
    bf16x8 ap1 = ld8(Pc + (16 + lm)*PST + lh*8);

    const unsigned short* Mc = &Mst[cur][0];
#pragma unroll
    for (int dt = 0; dt < 6; ++dt){
      bf16x8 bm = ld8(Mc + (dt*16 + lm)*MST + lh*8);
      out[0][dt] = mfma16(ap0, bm, out[0][dt]);
      out[1][dt] = mfma16(ap1, bm, out[1][dt]);
    }

    if (kt < 31){
      const int nxt = cur ^ 1;
      *reinterpret_cast<u16x8*>(&Kst[nxt][kr0*KST + kc0]) = g0;
      if (c1K) *reinterpret_cast<u16x8*>(&Kst[nxt][kr1*KST + kc1]) = g1;
      else     *reinterpret_cast<u16x8*>(&Mst[nxt][md1*MST + mc1]) = g1;
      *reinterpret_cast<u16x8*>(&Mst[nxt][md2*MST + mc2]) = g2;
    }
    __syncthreads();
  }

#pragma unroll
  for (int rt = 0; rt < 2; ++rt)
#pragma unroll
    for (int rg = 0; rg < 4; ++rg){
      float s = ssum[rt][rg];
#pragma unroll
      for (int off = 1; off < 16; off <<= 1) s += __shfl_xor(s, off);
      ssum[rt][rg] = 1.f / s;
    }

#pragma unroll
  for (int dt = 0; dt < 6; ++dt){
    float cvv = cv[(size_t)bh*96 + dt*16 + lm];
#pragma unroll
    for (int rt = 0; rt < 2; ++rt)
#pragma unroll
      for (int rg = 0; rg < 4; ++rg){
        int row = q0 + rt*16 + lh*4 + rg;
        xh[((size_t)bh*1024 + row)*96 + dt*16 + lm] =
            f2bf(out[rt][dt][rg]*ssum[rt][rg] + cvv);
      }
  }
}

// ---------------------------------------------------------------------------
// Projection (R10): out[t][o] = sum_i xh[t][i]*Wpt[o][i] + b_proj[o].
// Block = 128 tokens x 96 outputs; 4 waves x 32 tokens; staged Wpt tile.
// ---------------------------------------------------------------------------
__global__ __launch_bounds__(256, 2) void proj_kernel(
    const unsigned short* __restrict__ xh, const unsigned short* __restrict__ Wpt,
    const float* __restrict__ b_proj, float* __restrict__ out)
{
  constexpr int BST = 40;    // B-tile row stride (u16): 96 x 40
  __shared__ __align__(16) unsigned short Bst[2][96*BST];    // 15360 B

  const int mb = blockIdx.x;        // 0..63 -> 128 tokens
  const int nb = blockIdx.y;        // 0..7  -> 96 outputs
  const int tid = threadIdx.x;
  const int w = tid >> 6, lane = tid & 63, lh = lane >> 4, lm = lane & 15;
  const int t0 = mb*128 + w*32;
  const int o0 = nb*96;

  const int br0 = tid >> 2,          bc0 = (tid & 3)*8;
  const bool has1 = (tid < 128);
  const int br1 = (tid + 256) >> 2,  bc1 = ((tid + 256) & 3)*8;
  const unsigned short* Bsrc = Wpt + (size_t)o0*768;

  f32x4 acc[2][6];
#pragma unroll
  for (int rt = 0; rt < 2; ++rt)
#pragma unroll
    for (int nt = 0; nt < 6; ++nt) acc[rt][nt] = f32x4{0.f, 0.f, 0.f, 0.f};

  const int tok0 = t0 + lm, tok1 = t0 + 16 + lm;
  const int b0 = tok0 >> 10, n0_ = tok0 & 1023;
  const int b1 = tok1 >> 10, n1_ = tok1 & 1023;

  u16x8 g0, g1;
  g0 = *reinterpret_cast<const u16x8*>(Bsrc + (size_t)br0*768 + bc0);
  if (has1) g1 = *reinterpret_cast<const u16x8*>(Bsrc + (size_t)br1*768 + bc1);
  *reinterpret_cast<u16x8*>(&Bst[0][br0*BST + bc0]) = g0;
  if (has1) *reinterpret_cast<u16x8*>(&Bst[0][br1*BST + bc1]) = g1;
  __syncthreads();

  for (int kt = 0; kt < 24; ++kt){
    const int cur = kt & 1;

    if (kt < 23){
      const int ib = (kt+1)*32;
      g0 = *reinterpret_cast<const u16x8*>(Bsrc + (size_t)br0*768 + ib + bc0);
      if (has1) g1 = *reinterpret_cast<const u16x8*>(Bsrc + (size_t)br1*768 + ib + bc1);
    }

    const int h = kt/3, d0 = (kt - h*3)*32 + lh*8;
    bf16x8 a0 = ld8(xh + ((size_t)(b0*8 + h)*1024 + n0_)*96 + d0);
    bf16x8 a1 = ld8(xh + ((size_t)(b1*8 + h)*1024 + n1_)*96 + d0);

    const unsigned short* Bc = &Bst[cur][0];
#pragma unroll
    for (int nt = 0; nt < 6; ++nt){
      bf16x8 bv = ld8(Bc + (nt*16 + lm)*BST + lh*8);
      acc[0][nt] = mfma16(a0, bv, acc[0][nt]);
      acc[1][nt] = mfma16(a1, bv, acc[1][nt]);
    }

    if (kt < 23){
      const int nxt = cur ^ 1;
      *reinterpret_cast<u16x8*>(&Bst[nxt][br0*BST + bc0]) = g0;
      if (has1) *reinterpret_cast<u16x8*>(&Bst[nxt][br1*BST + bc1]) = g1;
    }
    __syncthreads();
  }

#pragma unroll
  for (int nt = 0; nt < 6; ++nt){
    int o = o0 + nt*16 + lm;
    float bias = b_proj[o];
#pragma unroll
    for (int rt = 0; rt < 2; ++rt)
#pragma unroll
      for (int rg = 0; rg < 4; ++rg)
        out[(size_t)(t0 + rt*16 + lh*4 + rg)*768 + o] = acc[rt][nt][rg] + bias;
  }
}

// ---------------------------------------------------------------------------
extern "C" void kernel_launch(void* const* d_in, const int* in_sizes, int n_in,
                              void* d_out, int out_size, void* d_ws, size_t ws_size,
                              hipStream_t stream)
{
  (void)in_sizes; (void)n_in; (void)out_size; (void)ws_size;
  const float* q      = (const float*)d_in[0];
  const float* k      = (const float*)d_in[1];
  const float* v      = (const float*)d_in[2];
  const float* wq     = (const float*)d_in[3];
  const float* wk     = (const float*)d_in[4];
  const float* wv     = (const float*)d_in[5];
  const float* w_re   = (const float*)d_in[6];
  const float* b_re   = (const float*)d_in[7];
  const float* gma    = (const float*)d_in[8];
  const float* beta   = (const float*)d_in[9];
  const float* mean   = (const float*)d_in[10];
  const float* var    = (const float*)d_in[11];
  const float* w_proj = (const float*)d_in[12];
  const float* b_proj = (const float*)d_in[13];
  float* out = (float*)d_out;

  // ws layout (bytes): total ~66.3 MB. vh aliases the xh slot (vh is dead
  // before attn writes xh).
  char* ws = (char*)d_ws;
  unsigned short* qh     = (unsigned short*)(ws + 0);          // 12,582,912
  unsigned short* kh     = (unsigned short*)(ws + 12582912);   // 12,582,912
  unsigned short* vtg    = (unsigned short*)(ws + 25165824);   // 12,582,912
  unsigned short* xh     = (unsigned short*)(ws + 37748736);   // 12,582,912
  unsigned short* vh     = xh;                                 // alias (dead before attn)
  unsigned short* Wre_rm = (unsigned short*)(ws + 50331648);   //  2,097,152
  unsigned short* Wpt    = (unsigned short*)(ws + 52428800);   //  1,179,648
  unsigned short* M2t    = (unsigned short*)(ws + 53608448);   // 12,582,912
  float*          G      = (float*)(ws + 66191360);            //      4,096
  float*          Cc     = (float*)(ws + 66195456);            //      4,096
  float*          CoverG = (float*)(ws + 66199552);            //      4,096
  float*          cv     = (float*)(ws + 66203648);            //     24,576

  prep_kernel<<<dim3(4100), dim3(256), 0, stream>>>(w_re, b_re, gma, beta, mean, var,
                                                    Wre_rm, G, Cc, CoverG);
  wpt_kernel<<<dim3(12, 12), dim3(256), 0, stream>>>(w_proj, Wpt);
  conv_kernel<<<dim3(2048, 3), dim3(256), 0, stream>>>(q, k, v, wq, wk, wv, G, qh, kh, vh);
  vt_kernel<<<dim3(8, 64), dim3(256), 0, stream>>>(vh, vtg);
  cv_kernel<<<dim3(512), dim3(256), 0, stream>>>(vtg, CoverG, cv);
  m2_kernel<<<dim3(512), dim3(256), 0, stream>>>(Wre_rm, vtg, M2t);
  attn_kernel<<<dim3(512), dim3(256), 0, stream>>>(qh, kh, M2t, cv, xh);
  proj_kernel<<<dim3(64, 8), dim3(256), 0, stream>>>(xh, Wpt, b_proj, out);
}

// Round 13
// 152.744 us; speedup vs baseline: 1.1371x; 1.1371x over previous
//
#include <hip/hip_runtime.h>
#include <hip/hip_bf16.h>

// Sizes
// B=8, N=1024, S=16, C=3, H=8, DIM=768, HD=96, SCALE=96^-0.5, BN_EPS=1e-3
//
// Algebraic restructuring (R5): out = BN(P@W_re)@V collapses to
//   out[n][d] = sum_m P[n][m] * M2[m][d] + cv[d]
//   M2[m][d]  = sum_p W_re[m][p] * G[p] * V[p][d]      (12.9 GF, batched bh)
//   cv[d]     = sum_p Cc[p] * V[p][d]
// R13: conv fixed — weights loaded from GLOBAL with uniform compile-time
//      indices (-> SGPRs via s_load, no LDS weight re-reads), x staged as
//      scalar 18x55-stride zero-halo tile (27 unconditional ds_read_b32,
//      ~2-way banks). R12's float4 tile (8-way conflicts) and LDS-sourced
//      wreg (refolded by compiler) both reverted.

typedef __attribute__((ext_vector_type(4))) float f32x4;
typedef __bf16 __attribute__((ext_vector_type(8))) bf16x8;
typedef unsigned short u16x8 __attribute__((ext_vector_type(8)));

__device__ __forceinline__ unsigned short f2bf(float x){
  unsigned u = __builtin_bit_cast(unsigned, x);
  u += 0x7fffu + ((u >> 16) & 1u);          // round-to-nearest-even
  return (unsigned short)(u >> 16);
}

__device__ __forceinline__ float bf2f(unsigned short u){
  unsigned v = (unsigned)u << 16;
  return __builtin_bit_cast(float, v);
}

__device__ __forceinline__ f32x4 mfma16(bf16x8 a, bf16x8 b, f32x4 c){
  return __builtin_amdgcn_mfma_f32_16x16x32_bf16(a, b, c, 0, 0, 0);
}

__device__ __forceinline__ bf16x8 ld8(const unsigned short* p){
  return *reinterpret_cast<const bf16x8*>(p);
}

// ---------------------------------------------------------------------------
// Prep: Wre_rm[m][p] = bf16(w_re[m][p]) (coalesced cast);
//       G[p] = gamma*rsqrt(var+eps); Cc=(b_re-mean)*G+beta; CoverG=Cc/G
// ---------------------------------------------------------------------------
__global__ void prep_kernel(const float* __restrict__ w_re, const float* __restrict__ b_re,
                            const float* __restrict__ gma, const float* __restrict__ beta,
                            const float* __restrict__ mean, const float* __restrict__ var,
                            unsigned short* __restrict__ Wre_rm,
                            float* __restrict__ G, float* __restrict__ Cc,
                            float* __restrict__ CoverG)
{
  int idx = blockIdx.x * 256 + threadIdx.x;
  if (idx < 1024*1024){
    Wre_rm[idx] = f2bf(w_re[idx]);
  } else if (idx < 1024*1024 + 1024){
    int p = idx - 1024*1024;
    float g = gma[p] * rsqrtf(var[p] + 1e-3f);
    float cc = (b_re[p] - mean[p]) * g + beta[p];
    G[p] = g;
    Cc[p] = cc;
    CoverG[p] = cc / g;
  }
}

// ---------------------------------------------------------------------------
// Wpt[o][i] = bf16(w_proj[i][o]) via LDS 64x64 tiles (coalesced both sides)
// ---------------------------------------------------------------------------
__global__ __launch_bounds__(256) void wpt_kernel(const float* __restrict__ wp,
                                                  unsigned short* __restrict__ Wpt)
{
  __shared__ float t[64][65];
  const int i0 = blockIdx.x * 64, o0 = blockIdx.y * 64;
  const int r = threadIdx.x >> 6;        // 0..3
  const int c = threadIdx.x & 63;        // 0..63
#pragma unroll
  for (int rep = 0; rep < 16; ++rep){
    int row = rep*4 + r;
    t[row][c] = wp[(size_t)(i0 + row)*768 + o0 + c];
  }
  __syncthreads();
#pragma unroll
  for (int rep = 0; rep < 16; ++rep){
    int orow = rep*4 + r;
    Wpt[(size_t)(o0 + orow)*768 + i0 + c] = f2bf(t[c][orow]);
  }
}

// ---------------------------------------------------------------------------
// Conv 3x3 SAME (R13); 4 tokens/block, pixel-per-thread.
// Weights: SGPR-resident (uniform global loads, compile-time indices).
// x: scalar zero-halo tile 18 rows x 55-float stride (27 unconditional
// ds_read_b32 per token, ~2-way banks). qh/kh/vh [B,H,N,96]; vh scaled G[n].
// ---------------------------------------------------------------------------
__global__ __launch_bounds__(256) void conv_kernel(
    const float* __restrict__ q, const float* __restrict__ k,
    const float* __restrict__ v,
    const float* __restrict__ wq, const float* __restrict__ wk,
    const float* __restrict__ wv,
    const float* __restrict__ G,
    unsigned short* __restrict__ qh, unsigned short* __restrict__ kh,
    unsigned short* __restrict__ vh)
{
  constexpr int XR = 55;             // padded row stride (floats); 54 used
  const int tb = blockIdx.x;         // 0..2047 (4 tokens each)
  const int which = blockIdx.y;      // 0=q 1=k 2=v
  const float* x = (which == 0) ? q : (which == 1) ? k : v;
  const float* w = (which == 0) ? wq : (which == 1) ? wk : wv;
  unsigned short* dst = (which == 0) ? qh : (which == 1) ? kh : vh;

  __shared__ float xs[4][18*XR];     // 15840 B
  const int tid = threadIdx.x;

  // weights -> SGPRs: uniform pointer + compile-time offsets => s_load
  float wreg[81];
#pragma unroll
  for (int i = 0; i < 81; ++i) wreg[i] = w[i];

  // zero-fill halo, then interior fill
  {
    float* base = &xs[0][0];
    for (int i = tid; i < 4*18*XR; i += 256) base[i] = 0.f;
  }
  __syncthreads();
  for (int i = tid; i < 4*768; i += 256){
    int tk = i / 768, p = i - tk*768;
    int pix = p / 3, ci = p - pix*3;
    int r = pix >> 4, c = pix & 15;
    xs[tk][(r + 1)*XR + (c + 1)*3 + ci] = x[(size_t)tb*4*768 + i];
  }
  __syncthreads();

  const int pix = tid;               // 0..255
  const int c = pix & 15, r = pix >> 4;

#pragma unroll
  for (int tk = 0; tk < 4; ++tk){
    const float* xt = &xs[tk][r*XR + c*3];   // (r+dr)*XR + (c+dc)*3 with halo offset folded
    float a0 = 0.f, a1 = 0.f, a2 = 0.f;
#pragma unroll
    for (int dr = 0; dr < 3; ++dr){
#pragma unroll
      for (int dc = 0; dc < 3; ++dc){
#pragma unroll
        for (int ci = 0; ci < 3; ++ci){
          float xv = xt[dr*XR + dc*3 + ci];
          const int wb = (dr*3 + dc)*9 + ci*3;
          a0 += xv * wreg[wb + 0];
          a1 += xv * wreg[wb + 1];
          a2 += xv * wreg[wb + 2];
        }
      }
    }
    const int token = tb*4 + tk;
    const int b = token >> 10, n = token & 1023;
    const float gs = (which == 2) ? G[n] : 1.f;
    float av[3] = {a0*gs, a1*gs, a2*gs};
#pragma unroll
    for (int co = 0; co < 3; ++co){
      int f = pix*3 + co;                   // head boundary (96) never splits a thread
      int h = f / 96, d = f - h*96;
      dst[((size_t)(b*8 + h)*1024 + n)*96 + d] = f2bf(av[co]);
    }
  }
}

// ---------------------------------------------------------------------------
// Transpose vh[bh][n][96] -> vtg[bh][d][n] via LDS tile, coalesced both sides.
// Grid (8 n-chunks, 64 bh).
// ---------------------------------------------------------------------------
__global__ __launch_bounds__(256) void vt_kernel(const unsigned short* __restrict__ vh,
                                                 unsigned short* __restrict__ vtg)
{
  __shared__ unsigned short t[96*136];       // row d: stride 136 (272 B, 16B-aligned, odd*16B)
  const int chunk = blockIdx.x;              // 0..7
  const int bh = blockIdx.y;                 // 0..63
  const int n0 = chunk*128;
  const int tid = threadIdx.x;

  const unsigned short* src = vh + ((size_t)bh*1024 + n0)*96;
#pragma unroll
  for (int it = 0; it < 6; ++it){
    int idx = it*256 + tid;                  // 0..1535
    int row = idx / 12, v = idx - row*12;    // row 0..127, v 0..11
    u16x8 xv = *reinterpret_cast<const u16x8*>(src + row*96 + v*8);
#pragma unroll
    for (int j = 0; j < 8; ++j) t[(v*8 + j)*136 + row] = xv[j];
  }
  __syncthreads();

  unsigned short* dstp = vtg + (size_t)bh*96*1024 + n0;
#pragma unroll
  for (int it = 0; it < 6; ++it){
    int idx = it*256 + tid;                  // 0..1535
    int d = idx >> 4, ch = idx & 15;         // d 0..95, ch 0..15
    u16x8 xv = *reinterpret_cast<const u16x8*>(&t[d*136 + ch*8]);
    *reinterpret_cast<u16x8*>(dstp + (size_t)d*1024 + ch*8) = xv;
  }
}

// ---------------------------------------------------------------------------
// cv[bh][d] = sum_p CoverG[p] * vtg[bh][d][p]   (= sum_p Cc[p]*V[p][d])
// Grid 512: block = (bh, 12-d chunk); each wave handles 3 d's.
// ---------------------------------------------------------------------------
__global__ __launch_bounds__(256) void cv_kernel(const unsigned short* __restrict__ vtg,
                                                 const float* __restrict__ CoverG,
                                                 float* __restrict__ cv)
{
  const int id = blockIdx.x;
  const int bh = id >> 3;
  const int d0 = (id & 7) * 12;
  const int tid = threadIdx.x;
  const int w = tid >> 6, lane = tid & 63;
  const unsigned short* vb = vtg + (size_t)bh * 96 * 1024;

#pragma unroll
  for (int dd = 0; dd < 3; ++dd){
    int d = d0 + w*3 + dd;
    const unsigned short* row = vb + (size_t)d * 1024;
    float s = 0.f;
#pragma unroll
    for (int j = 0; j < 16; ++j){
      int p = j*64 + lane;
      s += CoverG[p] * bf2f(row[p]);
    }
#pragma unroll
    for (int off = 1; off < 64; off <<= 1) s += __shfl_xor(s, off);
    if (lane == 0) cv[(size_t)bh*96 + d] = s;
  }
}

// ---------------------------------------------------------------------------
// M2t[bh][d][m] = sum_p Wre_rm[m][p] * vtg[bh][d][p]   (K = 1024 over p)
// R11: block-staged double-buffered W-tile (128x32) + V-tile (96x32);
// 4 waves x 32 m-rows; 12 MFMA/wave-iter; one barrier/iter.
// ---------------------------------------------------------------------------
__global__ __launch_bounds__(256, 2) void m2_kernel(
    const unsigned short* __restrict__ Wre_rm, const unsigned short* __restrict__ vtg,
    unsigned short* __restrict__ M2t)
{
  constexpr int WST = 40;   // W-tile row stride (u16): 128 x 40
  constexpr int VST = 40;   // V-tile row stride (u16): 96 x 40
  __shared__ __align__(16) unsigned short Wst[2][128*WST];   // 20480 B
  __shared__ __align__(16) unsigned short Vst[2][96*VST];    // 15360 B -> 35840 B

  const int id = blockIdx.x;             // 0..511
  const int xcd = id & 7, slot = id >> 3;
  const int mtile = slot & 7;            // 0..7
  const int bh = xcd + ((slot >> 3) << 3);
  const int tid = threadIdx.x;
  const int w = tid >> 6, lane = tid & 63, lh = lane >> 4, lm = lane & 15;
  const int m0 = mtile*128;              // block's m-base
  const int mw = w*32;                   // wave's m offset in tile

  const unsigned short* vb = vtg + (size_t)bh * 96 * 1024;
  const unsigned short* Wb = Wre_rm + (size_t)m0 * 1024;

  const int cr = tid >> 2, cc0 = (tid & 3)*8;
  const bool has3 = (tid < 128);

  f32x4 acc[2][6];
#pragma unroll
  for (int rt = 0; rt < 2; ++rt)
#pragma unroll
    for (int dt = 0; dt < 6; ++dt)
      acc[rt][dt] = f32x4{0.f, 0.f, 0.f, 0.f};

  // --- prologue: stage p-tile 0 into buffer 0 ---
  u16x8 g0, g1, g2, g3;
  g0 = *reinterpret_cast<const u16x8*>(Wb + (size_t)cr*1024 + cc0);
  g1 = *reinterpret_cast<const u16x8*>(Wb + (size_t)(64 + cr)*1024 + cc0);
  g2 = *reinterpret_cast<const u16x8*>(vb + (size_t)cr*1024 + cc0);
  if (has3) g3 = *reinterpret_cast<const u16x8*>(vb + (size_t)(64 + cr)*1024 + cc0);
  *reinterpret_cast<u16x8*>(&Wst[0][cr*WST + cc0]) = g0;
  *reinterpret_cast<u16x8*>(&Wst[0][(64 + cr)*WST + cc0]) = g1;
  *reinterpret_cast<u16x8*>(&Vst[0][cr*VST + cc0]) = g2;
  if (has3) *reinterpret_cast<u16x8*>(&Vst[0][(64 + cr)*VST + cc0]) = g3;
  __syncthreads();

  for (int ks = 0; ks < 32; ++ks){
    const int cur = ks & 1;

    if (ks < 31){
      const int p0 = (ks+1)*32;
      g0 = *reinterpret_cast<const u16x8*>(Wb + (size_t)cr*1024 + p0 + cc0);
      g1 = *reinterpret_cast<const u16x8*>(Wb + (size_t)(64 + cr)*1024 + p0 + cc0);
      g2 = *reinterpret_cast<const u16x8*>(vb + (size_t)cr*1024 + p0 + cc0);
      if (has3) g3 = *reinterpret_cast<const u16x8*>(vb + (size_t)(64 + cr)*1024 + p0 + cc0);
    }

    const unsigned short* Wc = &Wst[cur][0];
    const unsigned short* Vc = &Vst[cur][0];
    bf16x8 aW0 = ld8(Wc + (mw + lm)*WST + lh*8);
    bf16x8 aW1 = ld8(Wc + (mw + 16 + lm)*WST + lh*8);
#pragma unroll
    for (int dt = 0; dt < 6; ++dt){
      bf16x8 bV = ld8(Vc + (dt*16 + lm)*VST + lh*8);
      acc[0][dt] = mfma16(aW0, bV, acc[0][dt]);
      acc[1][dt] = mfma16(aW1, bV, acc[1][dt]);
    }

    if (ks < 31){
      const int nxt = cur ^ 1;
      *reinterpret_cast<u16x8*>(&Wst[nxt][cr*WST + cc0]) = g0;
      *reinterpret_cast<u16x8*>(&Wst[nxt][(64 + cr)*WST + cc0]) = g1;
      *reinterpret_cast<u16x8*>(&Vst[nxt][cr*VST + cc0]) = g2;
      if (has3) *reinterpret_cast<u16x8*>(&Vst[nxt][(64 + cr)*VST + cc0]) = g3;
    }
    __syncthreads();
  }

#pragma unroll
  for (int rt = 0; rt < 2; ++rt)
#pragma unroll
    for (int dt = 0; dt < 6; ++dt)
#pragma unroll
      for (int rg = 0; rg < 4; ++rg){
        int m = m0 + mw + rt*16 + lh*4 + rg;
        int d = dt*16 + lm;
        M2t[((size_t)bh*96 + d)*1024 + m] = f2bf(acc[rt][dt][rg]);
      }
}

// ---------------------------------------------------------------------------
// Fused attention (R9): block-staged K/M2 tiles, double-buffered.
// 256 thr = 4 waves; block owns 128 q-rows of one bh; wave w: 32 rows.
// ---------------------------------------------------------------------------
__global__ __launch_bounds__(256, 2) void attn_kernel(
    const unsigned short* __restrict__ qh, const unsigned short* __restrict__ kh,
    const unsigned short* __restrict__ M2t, const float* __restrict__ cv,
    unsigned short* __restrict__ xh)
{
  constexpr int KST = 104;   // K-tile row stride (u16): 32 x 104
  constexpr int MST = 40;    // M-tile row stride (u16): 96 x 40
  constexpr int PST = 40;    // P stage row stride (u16): 32 x 40 per wave
  __shared__ __align__(16) unsigned short Kst[2][32*KST];    // 13312 B
  __shared__ __align__(16) unsigned short Mst[2][96*MST];    // 15360 B
  __shared__ __align__(16) unsigned short Pst[2][4][32*PST]; // 20480 B -> total 49152 B

  const int id = blockIdx.x;             // 0..511
  const int xcd = id & 7, slot = id >> 3;
  const int chunk = slot & 7;            // 128-row chunk
  const int bh = xcd + ((slot >> 3) << 3);
  const int tid = threadIdx.x;
  const int w = tid >> 6;                // 0..3
  const int lane = tid & 63;
  const int lh = lane >> 4;              // 0..3
  const int lm = lane & 15;              // 0..15
  const int q0 = chunk*128 + w*32;       // this wave's 32 q-rows

  const unsigned short* Qb = qh + (size_t)bh * 1024 * 96;
  const unsigned short* Kb = kh + (size_t)bh * 1024 * 96;
  const unsigned short* Mb = M2t + (size_t)bh * 96 * 1024;

  const int kr0 = tid/12,  kc0 = (tid%12)*8;
  const bool c1K = (tid < 128);
  const int t1 = tid + 256;
  const int kr1 = c1K ? t1/12 : 0,  kc1 = c1K ? (t1%12)*8 : 0;
  const int md1 = c1K ? 0 : (tid-128)>>2, mc1 = c1K ? 0 : ((tid-128)&3)*8;
  const int md2 = (tid+128)>>2, mc2 = ((tid+128)&3)*8;

  bf16x8 aq[2][3];
#pragma unroll
  for (int rt = 0; rt < 2; ++rt)
#pragma unroll
    for (int kq = 0; kq < 3; ++kq)
      aq[rt][kq] = ld8(Qb + (size_t)(q0 + rt*16 + lm)*96 + kq*32 + lh*8);

  f32x4 out[2][6];
#pragma unroll
  for (int rt = 0; rt < 2; ++rt)
#pragma unroll
    for (int dt = 0; dt < 6; ++dt) out[rt][dt] = f32x4{0.f, 0.f, 0.f, 0.f};
  f32x4 ssum[2] = {f32x4{0.f,0.f,0.f,0.f}, f32x4{0.f,0.f,0.f,0.f}};

  const float SCALE = 0.10206207261596577f;

  u16x8 g0, g1, g2;
  {
    g0 = *reinterpret_cast<const u16x8*>(Kb + (size_t)kr0*96 + kc0);
    g1 = c1K ? *reinterpret_cast<const u16x8*>(Kb + (size_t)kr1*96 + kc1)
             : *reinterpret_cast<const u16x8*>(Mb + (size_t)md1*1024 + mc1);
    g2 = *reinterpret_cast<const u16x8*>(Mb + (size_t)md2*1024 + mc2);
    *reinterpret_cast<u16x8*>(&Kst[0][kr0*KST + kc0]) = g0;
    if (c1K) *reinterpret_cast<u16x8*>(&Kst[0][kr1*KST + kc1]) = g1;
    else     *reinterpret_cast<u16x8*>(&Mst[0][md1*MST + mc1]) = g1;
    *reinterpret_cast<u16x8*>(&Mst[0][md2*MST + mc2]) = g2;
  }
  __syncthreads();

  for (int kt = 0; kt < 32; ++kt){
    const int cur = kt & 1;

    if (kt < 31){
      const int kb = (kt+1)*32;
      g0 = *reinterpret_cast<const u16x8*>(Kb + (size_t)(kb + kr0)*96 + kc0);
      g1 = c1K ? *reinterpret_cast<const u16x8*>(Kb + (size_t)(kb + kr1)*96 + kc1)
               : *reinterpret_cast<const u16x8*>(Mb + (size_t)md1*1024 + kb + mc1);
      g2 = *reinterpret_cast<const u16x8*>(Mb + (size_t)md2*1024 + kb + mc2);
    }

    const unsigned short* Kc = &Kst[cur][0];
    f32x4 sacc[2][2];
    sacc[0][0] = f32x4{0.f,0.f,0.f,0.f}; sacc[0][1] = f32x4{0.f,0.f,0.f,0.f};
    sacc[1][0] = f32x4{0.f,0.f,0.f,0.f}; sacc[1][1] = f32x4{0.f,0.f,0.f,0.f};
#pragma unroll
    for (int kq = 0; kq < 3; ++kq){
      bf16x8 bk0 = ld8(Kc + lm*KST        + kq*32 + lh*8);
      bf16x8 bk1 = ld8(Kc + (16 + lm)*KST + kq*32 + lh*8);
      sacc[0][0] = mfma16(aq[0][kq], bk0, sacc[0][0]);
      sacc[0][1] = mfma16(aq[0][kq], bk1, sacc[0][1]);
      sacc[1][0] = mfma16(aq[1][kq], bk0, sacc[1][0]);
      sacc[1][1] = mfma16(aq[1][kq], bk1, sacc[1][1]);
    }

    unsigned short* Pc = &Pst[cur][w][0];
#pragma unroll
    for (int rt = 0; rt < 2; ++rt)
#pragma unroll
      for (int nt = 0; nt < 2; ++nt)
#pragma unroll
        for (int rg = 0; rg < 4; ++rg){
          float e = __expf(sacc[rt][nt][rg] * SCALE);
          ssum[rt][rg] += e;
          Pc[(rt*16 + lh*4 + rg)*PST + nt*16 + lm] = f2bf(e);
        }

    bf16x8 ap0 = ld8(Pc + lm*PST        + lh*8);
    bf16x8 ap1 = ld8(Pc + (16 + lm)*PST + lh*8);

    const unsigned short* Mc = &Mst[cur][0];
#pragma unroll
    for (int dt = 0; dt < 6; ++dt){
      bf16x8 bm = ld8(Mc + (dt*16 + lm)*MST + lh*8);
      out[0][dt] = mfma16(ap0, bm, out[0][dt]);
      out[1][dt] = mfma16(ap1, bm, out[1][dt]);
    }

    if (kt < 31){
      const int nxt = cur ^ 1;
      *reinterpret_cast<u16x8*>(&Kst[nxt][kr0*KST + kc0]) = g0;
      if (c1K) *reinterpret_cast<u16x8*>(&Kst[nxt][kr1*KST + kc1]) = g1;
      else     *reinterpret_cast<u16x8*>(&Mst[nxt][md1*MST + mc1]) = g1;
      *reinterpret_cast<u16x8*>(&Mst[nxt][md2*MST + mc2]) = g2;
    }
    __syncthreads();
  }

#pragma unroll
  for (int rt = 0; rt < 2; ++rt)
#pragma unroll
    for (int rg = 0; rg < 4; ++rg){
      float s = ssum[rt][rg];
#pragma unroll
      for (int off = 1; off < 16; off <<= 1) s += __shfl_xor(s, off);
      ssum[rt][rg] = 1.f / s;
    }

#pragma unroll
  for (int dt = 0; dt < 6; ++dt){
    float cvv = cv[(size_t)bh*96 + dt*16 + lm];
#pragma unroll
    for (int rt = 0; rt < 2; ++rt)
#pragma unroll
      for (int rg = 0; rg < 4; ++rg){
        int row = q0 + rt*16 + lh*4 + rg;
        xh[((size_t)bh*1024 + row)*96 + dt*16 + lm] =
            f2bf(out[rt][dt][rg]*ssum[rt][rg] + cvv);
      }
  }
}

// ---------------------------------------------------------------------------
// Projection (R10): out[t][o] = sum_i xh[t][i]*Wpt[o][i] + b_proj[o].
// Block = 128 tokens x 96 outputs; 4 waves x 32 tokens; staged Wpt tile.
// ---------------------------------------------------------------------------
__global__ __launch_bounds__(256, 2) void proj_kernel(
    const unsigned short* __restrict__ xh, const unsigned short* __restrict__ Wpt,
    const float* __restrict__ b_proj, float* __restrict__ out)
{
  constexpr int BST = 40;    // B-tile row stride (u16): 96 x 40
  __shared__ __align__(16) unsigned short Bst[2][96*BST];    // 15360 B

  const int mb = blockIdx.x;        // 0..63 -> 128 tokens
  const int nb = blockIdx.y;        // 0..7  -> 96 outputs
  const int tid = threadIdx.x;
  const int w = tid >> 6, lane = tid & 63, lh = lane >> 4, lm = lane & 15;
  const int t0 = mb*128 + w*32;
  const int o0 = nb*96;

  const int br0 = tid >> 2,          bc0 = (tid & 3)*8;
  const bool has1 = (tid < 128);
  const int br1 = (tid + 256) >> 2,  bc1 = ((tid + 256) & 3)*8;
  const unsigned short* Bsrc = Wpt + (size_t)o0*768;

  f32x4 acc[2][6];
#pragma unroll
  for (int rt = 0; rt < 2; ++rt)
#pragma unroll
    for (int nt = 0; nt < 6; ++nt) acc[rt][nt] = f32x4{0.f, 0.f, 0.f, 0.f};

  const int tok0 = t0 + lm, tok1 = t0 + 16 + lm;
  const int b0 = tok0 >> 10, n0_ = tok0 & 1023;
  const int b1 = tok1 >> 10, n1_ = tok1 & 1023;

  u16x8 g0, g1;
  g0 = *reinterpret_cast<const u16x8*>(Bsrc + (size_t)br0*768 + bc0);
  if (has1) g1 = *reinterpret_cast<const u16x8*>(Bsrc + (size_t)br1*768 + bc1);
  *reinterpret_cast<u16x8*>(&Bst[0][br0*BST + bc0]) = g0;
  if (has1) *reinterpret_cast<u16x8*>(&Bst[0][br1*BST + bc1]) = g1;
  __syncthreads();

  for (int kt = 0; kt < 24; ++kt){
    const int cur = kt & 1;

    if (kt < 23){
      const int ib = (kt+1)*32;
      g0 = *reinterpret_cast<const u16x8*>(Bsrc + (size_t)br0*768 + ib + bc0);
      if (has1) g1 = *reinterpret_cast<const u16x8*>(Bsrc + (size_t)br1*768 + ib + bc1);
    }

    const int h = kt/3, d0 = (kt - h*3)*32 + lh*8;
    bf16x8 a0 = ld8(xh + ((size_t)(b0*8 + h)*1024 + n0_)*96 + d0);
    bf16x8 a1 = ld8(xh + ((size_t)(b1*8 + h)*1024 + n1_)*96 + d0);

    const unsigned short* Bc = &Bst[cur][0];
#pragma unroll
    for (int nt = 0; nt < 6; ++nt){
      bf16x8 bv = ld8(Bc + (nt*16 + lm)*BST + lh*8);
      acc[0][nt] = mfma16(a0, bv, acc[0][nt]);
      acc[1][nt] = mfma16(a1, bv, acc[1][nt]);
    }

    if (kt < 23){
      const int nxt = cur ^ 1;
      *reinterpret_cast<u16x8*>(&Bst[nxt][br0*BST + bc0]) = g0;
      if (has1) *reinterpret_cast<u16x8*>(&Bst[nxt][br1*BST + bc1]) = g1;
    }
    __syncthreads();
  }

#pragma unroll
  for (int nt = 0; nt < 6; ++nt){
    int o = o0 + nt*16 + lm;
    float bias = b_proj[o];
#pragma unroll
    for (int rt = 0; rt < 2; ++rt)
#pragma unroll
      for (int rg = 0; rg < 4; ++rg)
        out[(size_t)(t0 + rt*16 + lh*4 + rg)*768 + o] = acc[rt][nt][rg] + bias;
  }
}

// ---------------------------------------------------------------------------
extern "C" void kernel_launch(void* const* d_in, const int* in_sizes, int n_in,
                              void* d_out, int out_size, void* d_ws, size_t ws_size,
                              hipStream_t stream)
{
  (void)in_sizes; (void)n_in; (void)out_size; (void)ws_size;
  const float* q      = (const float*)d_in[0];
  const float* k      = (const float*)d_in[1];
  const float* v      = (const float*)d_in[2];
  const float* wq     = (const float*)d_in[3];
  const float* wk     = (const float*)d_in[4];
  const float* wv     = (const float*)d_in[5];
  const float* w_re   = (const float*)d_in[6];
  const float* b_re   = (const float*)d_in[7];
  const float* gma    = (const float*)d_in[8];
  const float* beta   = (const float*)d_in[9];
  const float* mean   = (const float*)d_in[10];
  const float* var    = (const float*)d_in[11];
  const float* w_proj = (const float*)d_in[12];
  const float* b_proj = (const float*)d_in[13];
  float* out = (float*)d_out;

  // ws layout (bytes): total ~66.3 MB. vh aliases the xh slot (vh is dead
  // before attn writes xh).
  char* ws = (char*)d_ws;
  unsigned short* qh     = (unsigned short*)(ws + 0);          // 12,582,912
  unsigned short* kh     = (unsigned short*)(ws + 12582912);   // 12,582,912
  unsigned short* vtg    = (unsigned short*)(ws + 25165824);   // 12,582,912
  unsigned short* xh     = (unsigned short*)(ws + 37748736);   // 12,582,912
  unsigned short* vh     = xh;                                 // alias (dead before attn)
  unsigned short* Wre_rm = (unsigned short*)(ws + 50331648);   //  2,097,152
  unsigned short* Wpt    = (unsigned short*)(ws + 52428800);   //  1,179,648
  unsigned short* M2t    = (unsigned short*)(ws + 53608448);   // 12,582,912
  float*          G      = (float*)(ws + 66191360);            //      4,096
  float*          Cc     = (float*)(ws + 66195456);            //      4,096
  float*          CoverG = (float*)(ws + 66199552);            //      4,096
  float*          cv     = (float*)(ws + 66203648);            //     24,576

  prep_kernel<<<dim3(4100), dim3(256), 0, stream>>>(w_re, b_re, gma, beta, mean, var,
                                                    Wre_rm, G, Cc, CoverG);
  wpt_kernel<<<dim3(12, 12), dim3(256), 0, stream>>>(w_proj, Wpt);
  conv_kernel<<<dim3(2048, 3), dim3(256), 0, stream>>>(q, k, v, wq, wk, wv, G, qh, kh, vh);
  vt_kernel<<<dim3(8, 64), dim3(256), 0, stream>>>(vh, vtg);
  cv_kernel<<<dim3(512), dim3(256), 0, stream>>>(vtg, CoverG, cv);
  m2_kernel<<<dim3(512), dim3(256), 0, stream>>>(Wre_rm, vtg, M2t);
  attn_kernel<<<dim3(512), dim3(256), 0, stream>>>(qh, kh, M2t, cv, xh);
  proj_kernel<<<dim3(64, 8), dim3(256), 0, stream>>>(xh, Wpt, b_proj, out);
}

// Round 14
// 145.588 us; speedup vs baseline: 1.1930x; 1.0492x over previous
//
#include <hip/hip_runtime.h>
#include <hip/hip_bf16.h>

// Sizes
// B=8, N=1024, S=16, C=3, H=8, DIM=768, HD=96, SCALE=96^-0.5, BN_EPS=1e-3
//
// Algebraic restructuring (R5): out = BN(P@W_re)@V collapses to
//   out[n][d] = sum_m P[n][m] * M2[m][d] + cv[d]
//   M2[m][d]  = sum_p W_re[m][p] * G[p] * V[p][d]      (12.9 GF, batched bh)
//   cv[d]     = sum_p Cc[p] * V[p][d]
// R14: conv drops LDS entirely — taps read straight from global (dwordx3,
//      L1-resident 12 KB/block working set), branchless clamp+mask halo,
//      weights SGPR-resident (R13 pattern). Conv was LDS-issue-bound
//      (108 ds_read_b32/thread ~ 31 us of LDS pipe); VMEM/L1 path is idle.

typedef __attribute__((ext_vector_type(4))) float f32x4;
typedef __bf16 __attribute__((ext_vector_type(8))) bf16x8;
typedef unsigned short u16x8 __attribute__((ext_vector_type(8)));

__device__ __forceinline__ unsigned short f2bf(float x){
  unsigned u = __builtin_bit_cast(unsigned, x);
  u += 0x7fffu + ((u >> 16) & 1u);          // round-to-nearest-even
  return (unsigned short)(u >> 16);
}

__device__ __forceinline__ float bf2f(unsigned short u){
  unsigned v = (unsigned)u << 16;
  return __builtin_bit_cast(float, v);
}

__device__ __forceinline__ f32x4 mfma16(bf16x8 a, bf16x8 b, f32x4 c){
  return __builtin_amdgcn_mfma_f32_16x16x32_bf16(a, b, c, 0, 0, 0);
}

__device__ __forceinline__ bf16x8 ld8(const unsigned short* p){
  return *reinterpret_cast<const bf16x8*>(p);
}

// ---------------------------------------------------------------------------
// Prep: Wre_rm[m][p] = bf16(w_re[m][p]) (coalesced cast);
//       G[p] = gamma*rsqrt(var+eps); Cc=(b_re-mean)*G+beta; CoverG=Cc/G
// ---------------------------------------------------------------------------
__global__ void prep_kernel(const float* __restrict__ w_re, const float* __restrict__ b_re,
                            const float* __restrict__ gma, const float* __restrict__ beta,
                            const float* __restrict__ mean, const float* __restrict__ var,
                            unsigned short* __restrict__ Wre_rm,
                            float* __restrict__ G, float* __restrict__ Cc,
                            float* __restrict__ CoverG)
{
  int idx = blockIdx.x * 256 + threadIdx.x;
  if (idx < 1024*1024){
    Wre_rm[idx] = f2bf(w_re[idx]);
  } else if (idx < 1024*1024 + 1024){
    int p = idx - 1024*1024;
    float g = gma[p] * rsqrtf(var[p] + 1e-3f);
    float cc = (b_re[p] - mean[p]) * g + beta[p];
    G[p] = g;
    Cc[p] = cc;
    CoverG[p] = cc / g;
  }
}

// ---------------------------------------------------------------------------
// Wpt[o][i] = bf16(w_proj[i][o]) via LDS 64x64 tiles (coalesced both sides)
// ---------------------------------------------------------------------------
__global__ __launch_bounds__(256) void wpt_kernel(const float* __restrict__ wp,
                                                  unsigned short* __restrict__ Wpt)
{
  __shared__ float t[64][65];
  const int i0 = blockIdx.x * 64, o0 = blockIdx.y * 64;
  const int r = threadIdx.x >> 6;        // 0..3
  const int c = threadIdx.x & 63;        // 0..63
#pragma unroll
  for (int rep = 0; rep < 16; ++rep){
    int row = rep*4 + r;
    t[row][c] = wp[(size_t)(i0 + row)*768 + o0 + c];
  }
  __syncthreads();
#pragma unroll
  for (int rep = 0; rep < 16; ++rep){
    int orow = rep*4 + r;
    Wpt[(size_t)(o0 + orow)*768 + i0 + c] = f2bf(t[c][orow]);
  }
}

// ---------------------------------------------------------------------------
// Conv 3x3 SAME (R14); 4 tokens/block, pixel-per-thread, NO LDS.
// Taps read directly from global (dwordx3; block working set 12 KB -> L1).
// Halo: branchless per-thread clamped offsets + 0/1 mask floats.
// Weights SGPR-resident. qh/kh/vh [B,H,N,96]; vh scaled by G[n].
// ---------------------------------------------------------------------------
__global__ __launch_bounds__(256) void conv_kernel(
    const float* __restrict__ q, const float* __restrict__ k,
    const float* __restrict__ v,
    const float* __restrict__ wq, const float* __restrict__ wk,
    const float* __restrict__ wv,
    const float* __restrict__ G,
    unsigned short* __restrict__ qh, unsigned short* __restrict__ kh,
    unsigned short* __restrict__ vh)
{
  const int tb = blockIdx.x;         // 0..2047 (4 tokens each)
  const int which = blockIdx.y;      // 0=q 1=k 2=v
  const float* x = (which == 0) ? q : (which == 1) ? k : v;
  const float* w = (which == 0) ? wq : (which == 1) ? wk : wv;
  unsigned short* dst = (which == 0) ? qh : (which == 1) ? kh : vh;

  // weights -> SGPRs (uniform pointer, compile-time offsets => s_load)
  float wreg[81];
#pragma unroll
  for (int i = 0; i < 81; ++i) wreg[i] = w[i];

  const int tid = threadIdx.x;       // pixel id 0..255
  const int c = tid & 15, r = tid >> 4;

  // per-thread tap masks and clamped offsets (computed once)
  float msk[9];
  int   off[9];
#pragma unroll
  for (int dr = 0; dr < 3; ++dr)
#pragma unroll
    for (int dc = 0; dc < 3; ++dc){
      int rr = r + dr - 1, cc = c + dc - 1;
      bool valid = (rr >= 0) && (rr < 16) && (cc >= 0) && (cc < 16);
      int rc = rr < 0 ? 0 : (rr > 15 ? 15 : rr);
      int cl = cc < 0 ? 0 : (cc > 15 ? 15 : cc);
      msk[dr*3 + dc] = valid ? 1.f : 0.f;
      off[dr*3 + dc] = (rc*16 + cl)*3;
    }

#pragma unroll
  for (int tk = 0; tk < 4; ++tk){
    const float* xt = x + ((size_t)(tb*4 + tk))*768;
    float a0 = 0.f, a1 = 0.f, a2 = 0.f;
#pragma unroll
    for (int j = 0; j < 9; ++j){
      const float* p = xt + off[j];
      float m = msk[j];
      float x0 = p[0]*m, x1 = p[1]*m, x2 = p[2]*m;   // -> global_load_dwordx3
      const int wb = j*9;
      a0 += x0*wreg[wb+0] + x1*wreg[wb+3] + x2*wreg[wb+6];
      a1 += x0*wreg[wb+1] + x1*wreg[wb+4] + x2*wreg[wb+7];
      a2 += x0*wreg[wb+2] + x1*wreg[wb+5] + x2*wreg[wb+8];
    }
    const int token = tb*4 + tk;
    const int b = token >> 10, n = token & 1023;
    const float gs = (which == 2) ? G[n] : 1.f;      // uniform per block -> s_load
    float av[3] = {a0*gs, a1*gs, a2*gs};
#pragma unroll
    for (int co = 0; co < 3; ++co){
      int f = tid*3 + co;                  // head boundary (96) never splits a thread
      int h = f / 96, d = f - h*96;
      dst[((size_t)(b*8 + h)*1024 + n)*96 + d] = f2bf(av[co]);
    }
  }
}

// ---------------------------------------------------------------------------
// Transpose vh[bh][n][96] -> vtg[bh][d][n] via LDS tile, coalesced both sides.
// Grid (8 n-chunks, 64 bh).
// ---------------------------------------------------------------------------
__global__ __launch_bounds__(256) void vt_kernel(const unsigned short* __restrict__ vh,
                                                 unsigned short* __restrict__ vtg)
{
  __shared__ unsigned short t[96*136];       // row d: stride 136 (272 B, 16B-aligned, odd*16B)
  const int chunk = blockIdx.x;              // 0..7
  const int bh = blockIdx.y;                 // 0..63
  const int n0 = chunk*128;
  const int tid = threadIdx.x;

  const unsigned short* src = vh + ((size_t)bh*1024 + n0)*96;
#pragma unroll
  for (int it = 0; it < 6; ++it){
    int idx = it*256 + tid;                  // 0..1535
    int row = idx / 12, v = idx - row*12;    // row 0..127, v 0..11
    u16x8 xv = *reinterpret_cast<const u16x8*>(src + row*96 + v*8);
#pragma unroll
    for (int j = 0; j < 8; ++j) t[(v*8 + j)*136 + row] = xv[j];
  }
  __syncthreads();

  unsigned short* dstp = vtg + (size_t)bh*96*1024 + n0;
#pragma unroll
  for (int it = 0; it < 6; ++it){
    int idx = it*256 + tid;                  // 0..1535
    int d = idx >> 4, ch = idx & 15;         // d 0..95, ch 0..15
    u16x8 xv = *reinterpret_cast<const u16x8*>(&t[d*136 + ch*8]);
    *reinterpret_cast<u16x8*>(dstp + (size_t)d*1024 + ch*8) = xv;
  }
}

// ---------------------------------------------------------------------------
// cv[bh][d] = sum_p CoverG[p] * vtg[bh][d][p]   (= sum_p Cc[p]*V[p][d])
// Grid 512: block = (bh, 12-d chunk); each wave handles 3 d's.
// ---------------------------------------------------------------------------
__global__ __launch_bounds__(256) void cv_kernel(const unsigned short* __restrict__ vtg,
                                                 const float* __restrict__ CoverG,
                                                 float* __restrict__ cv)
{
  const int id = blockIdx.x;
  const int bh = id >> 3;
  const int d0 = (id & 7) * 12;
  const int tid = threadIdx.x;
  const int w = tid >> 6, lane = tid & 63;
  const unsigned short* vb = vtg + (size_t)bh * 96 * 1024;

#pragma unroll
  for (int dd = 0; dd < 3; ++dd){
    int d = d0 + w*3 + dd;
    const unsigned short* row = vb + (size_t)d * 1024;
    float s = 0.f;
#pragma unroll
    for (int j = 0; j < 16; ++j){
      int p = j*64 + lane;
      s += CoverG[p] * bf2f(row[p]);
    }
#pragma unroll
    for (int off = 1; off < 64; off <<= 1) s += __shfl_xor(s, off);
    if (lane == 0) cv[(size_t)bh*96 + d] = s;
  }
}

// ---------------------------------------------------------------------------
// M2t[bh][d][m] = sum_p Wre_rm[m][p] * vtg[bh][d][p]   (K = 1024 over p)
// R11: block-staged double-buffered W-tile (128x32) + V-tile (96x32);
// 4 waves x 32 m-rows; 12 MFMA/wave-iter; one barrier/iter.
// ---------------------------------------------------------------------------
__global__ __launch_bounds__(256, 2) void m2_kernel(
    const unsigned short* __restrict__ Wre_rm, const unsigned short* __restrict__ vtg,
    unsigned short* __restrict__ M2t)
{
  constexpr int WST = 40;   // W-tile row stride (u16): 128 x 40
  constexpr int VST = 40;   // V-tile row stride (u16): 96 x 40
  __shared__ __align__(16) unsigned short Wst[2][128*WST];   // 20480 B
  __shared__ __align__(16) unsigned short Vst[2][96*VST];    // 15360 B -> 35840 B

  const int id = blockIdx.x;             // 0..511
  const int xcd = id & 7, slot = id >> 3;
  const int mtile = slot & 7;            // 0..7
  const int bh = xcd + ((slot >> 3) << 3);
  const int tid = threadIdx.x;
  const int w = tid >> 6, lane = tid & 63, lh = lane >> 4, lm = lane & 15;
  const int m0 = mtile*128;              // block's m-base
  const int mw = w*32;                   // wave's m offset in tile

  const unsigned short* vb = vtg + (size_t)bh * 96 * 1024;
  const unsigned short* Wb = Wre_rm + (size_t)m0 * 1024;

  const int cr = tid >> 2, cc0 = (tid & 3)*8;
  const bool has3 = (tid < 128);

  f32x4 acc[2][6];
#pragma unroll
  for (int rt = 0; rt < 2; ++rt)
#pragma unroll
    for (int dt = 0; dt < 6; ++dt)
      acc[rt][dt] = f32x4{0.f, 0.f, 0.f, 0.f};

  // --- prologue: stage p-tile 0 into buffer 0 ---
  u16x8 g0, g1, g2, g3;
  g0 = *reinterpret_cast<const u16x8*>(Wb + (size_t)cr*1024 + cc0);
  g1 = *reinterpret_cast<const u16x8*>(Wb + (size_t)(64 + cr)*1024 + cc0);
  g2 = *reinterpret_cast<const u16x8*>(vb + (size_t)cr*1024 + cc0);
  if (has3) g3 = *reinterpret_cast<const u16x8*>(vb + (size_t)(64 + cr)*1024 + cc0);
  *reinterpret_cast<u16x8*>(&Wst[0][cr*WST + cc0]) = g0;
  *reinterpret_cast<u16x8*>(&Wst[0][(64 + cr)*WST + cc0]) = g1;
  *reinterpret_cast<u16x8*>(&Vst[0][cr*VST + cc0]) = g2;
  if (has3) *reinterpret_cast<u16x8*>(&Vst[0][(64 + cr)*VST + cc0]) = g3;
  __syncthreads();

  for (int ks = 0; ks < 32; ++ks){
    const int cur = ks & 1;

    if (ks < 31){
      const int p0 = (ks+1)*32;
      g0 = *reinterpret_cast<const u16x8*>(Wb + (size_t)cr*1024 + p0 + cc0);
      g1 = *reinterpret_cast<const u16x8*>(Wb + (size_t)(64 + cr)*1024 + p0 + cc0);
      g2 = *reinterpret_cast<const u16x8*>(vb + (size_t)cr*1024 + p0 + cc0);
      if (has3) g3 = *reinterpret_cast<const u16x8*>(vb + (size_t)(64 + cr)*1024 + p0 + cc0);
    }

    const unsigned short* Wc = &Wst[cur][0];
    const unsigned short* Vc = &Vst[cur][0];
    bf16x8 aW0 = ld8(Wc + (mw + lm)*WST + lh*8);
    bf16x8 aW1 = ld8(Wc + (mw + 16 + lm)*WST + lh*8);
#pragma unroll
    for (int dt = 0; dt < 6; ++dt){
      bf16x8 bV = ld8(Vc + (dt*16 + lm)*VST + lh*8);
      acc[0][dt] = mfma16(aW0, bV, acc[0][dt]);
      acc[1][dt] = mfma16(aW1, bV, acc[1][dt]);
    }

    if (ks < 31){
      const int nxt = cur ^ 1;
      *reinterpret_cast<u16x8*>(&Wst[nxt][cr*WST + cc0]) = g0;
      *reinterpret_cast<u16x8*>(&Wst[nxt][(64 + cr)*WST + cc0]) = g1;
      *reinterpret_cast<u16x8*>(&Vst[nxt][cr*VST + cc0]) = g2;
      if (has3) *reinterpret_cast<u16x8*>(&Vst[nxt][(64 + cr)*VST + cc0]) = g3;
    }
    __syncthreads();
  }

#pragma unroll
  for (int rt = 0; rt < 2; ++rt)
#pragma unroll
    for (int dt = 0; dt < 6; ++dt)
#pragma unroll
      for (int rg = 0; rg < 4; ++rg){
        int m = m0 + mw + rt*16 + lh*4 + rg;
        int d = dt*16 + lm;
        M2t[((size_t)bh*96 + d)*1024 + m] = f2bf(acc[rt][dt][rg]);
      }
}

// ---------------------------------------------------------------------------
// Fused attention (R9): block-staged K/M2 tiles, double-buffered.
// 256 thr = 4 waves; block owns 128 q-rows of one bh; wave w: 32 rows.
// ---------------------------------------------------------------------------
__global__ __launch_bounds__(256, 2) void attn_kernel(
    const unsigned short* __restrict__ qh, const unsigned short* __restrict__ kh,
    const unsigned short* __restrict__ M2t, const float* __restrict__ cv,
    unsigned short* __restrict__ xh)
{
  constexpr int KST = 104;   // K-tile row stride (u16): 32 x 104
  constexpr int MST = 40;    // M-tile row stride (u16): 96 x 40
  constexpr int PST = 40;    // P stage row stride (u16): 32 x 40 per wave
  __shared__ __align__(16) unsigned short Kst[2][32*KST];    // 13312 B
  __shared__ __align__(16) unsigned short Mst[2][96*MST];    // 15360 B
  __shared__ __align__(16) unsigned short Pst[2][4][32*PST]; // 20480 B -> total 49152 B

  const int id = blockIdx.x;             // 0..511
  const int xcd = id & 7, slot = id >> 3;
  const int chunk = slot & 7;            // 128-row chunk
  const int bh = xcd + ((slot >> 3) << 3);
  const int tid = threadIdx.x;
  const int w = tid >> 6;                // 0..3
  const int lane = tid & 63;
  const int lh = lane >> 4;              // 0..3
  const int lm = lane & 15;              // 0..15
  const int q0 = chunk*128 + w*32;       // this wave's 32 q-rows

  const unsigned short* Qb = qh + (size_t)bh * 1024 * 96;
  const unsigned short* Kb = kh + (size_t)bh * 1024 * 96;
  const unsigned short* Mb = M2t + (size_t)bh * 96 * 1024;

  const int kr0 = tid/12,  kc0 = (tid%12)*8;
  const bool c1K = (tid < 128);
  const int t1 = tid + 256;
  const int kr1 = c1K ? t1/12 : 0,  kc1 = c1K ? (t1%12)*8 : 0;
  const int md1 = c1K ? 0 : (tid-128)>>2, mc1 = c1K ? 0 : ((tid-128)&3)*8;
  const int md2 = (tid+128)>>2, mc2 = ((tid+128)&3)*8;

  bf16x8 aq[2][3];
#pragma unroll
  for (int rt = 0; rt < 2; ++rt)
#pragma unroll
    for (int kq = 0; kq < 3; ++kq)
      aq[rt][kq] = ld8(Qb + (size_t)(q0 + rt*16 + lm)*96 + kq*32 + lh*8);

  f32x4 out[2][6];
#pragma unroll
  for (int rt = 0; rt < 2; ++rt)
#pragma unroll
    for (int dt = 0; dt < 6; ++dt) out[rt][dt] = f32x4{0.f, 0.f, 0.f, 0.f};
  f32x4 ssum[2] = {f32x4{0.f,0.f,0.f,0.f}, f32x4{0.f,0.f,0.f,0.f}};

  const float SCALE = 0.10206207261596577f;

  u16x8 g0, g1, g2;
  {
    g0 = *reinterpret_cast<const u16x8*>(Kb + (size_t)kr0*96 + kc0);
    g1 = c1K ? *reinterpret_cast<const u16x8*>(Kb + (size_t)kr1*96 + kc1)
             : *reinterpret_cast<const u16x8*>(Mb + (size_t)md1*1024 + mc1);
    g2 = *reinterpret_cast<const u16x8*>(Mb + (size_t)md2*1024 + mc2);
    *reinterpret_cast<u16x8*>(&Kst[0][kr0*KST + kc0]) = g0;
    if (c1K) *reinterpret_cast<u16x8*>(&Kst[0][kr1*KST + kc1]) = g1;
    else     *reinterpret_cast<u16x8*>(&Mst[0][md1*MST + mc1]) = g1;
    *reinterpret_cast<u16x8*>(&Mst[0][md2*MST + mc2]) = g2;
  }
  __syncthreads();

  for (int kt = 0; kt < 32; ++kt){
    const int cur = kt & 1;

    if (kt < 31){
      const int kb = (kt+1)*32;
      g0 = *reinterpret_cast<const u16x8*>(Kb + (size_t)(kb + kr0)*96 + kc0);
      g1 = c1K ? *reinterpret_cast<const u16x8*>(Kb + (size_t)(kb + kr1)*96 + kc1)
               : *reinterpret_cast<const u16x8*>(Mb + (size_t)md1*1024 + kb + mc1);
      g2 = *reinterpret_cast<const u16x8*>(Mb + (size_t)md2*1024 + kb + mc2);
    }

    const unsigned short* Kc = &Kst[cur][0];
    f32x4 sacc[2][2];
    sacc[0][0] = f32x4{0.f,0.f,0.f,0.f}; sacc[0][1] = f32x4{0.f,0.f,0.f,0.f};
    sacc[1][0] = f32x4{0.f,0.f,0.f,0.f}; sacc[1][1] = f32x4{0.f,0.f,0.f,0.f};
#pragma unroll
    for (int kq = 0; kq < 3; ++kq){
      bf16x8 bk0 = ld8(Kc + lm*KST        + kq*32 + lh*8);
      bf16x8 bk1 = ld8(Kc + (16 + lm)*KST + kq*32 + lh*8);
      sacc[0][0] = mfma16(aq[0][kq], bk0, sacc[0][0]);
      sacc[0][1] = mfma16(aq[0][kq], bk1, sacc[0][1]);
      sacc[1][0] = mfma16(aq[1][kq], bk0, sacc[1][0]);
      sacc[1][1] = mfma16(aq[1][kq], bk1, sacc[1][1]);
    }

    unsigned short* Pc = &Pst[cur][w][0];
#pragma unroll
    for (int rt = 0; rt < 2; ++rt)
#pragma unroll
      for (int nt = 0; nt < 2; ++nt)
#pragma unroll
        for (int rg = 0; rg < 4; ++rg){
          float e = __expf(sacc[rt][nt][rg] * SCALE);
          ssum[rt][rg] += e;
          Pc[(rt*16 + lh*4 + rg)*PST + nt*16 + lm] = f2bf(e);
        }

    bf16x8 ap0 = ld8(Pc + lm*PST        + lh*8);
    bf16x8 ap1 = ld8(Pc + (16 + lm)*PST + lh*8);

    const unsigned short* Mc = &Mst[cur][0];
#pragma unroll
    for (int dt = 0; dt < 6; ++dt){
      bf16x8 bm = ld8(Mc + (dt*16 + lm)*MST + lh*8);
      out[0][dt] = mfma16(ap0, bm, out[0][dt]);
      out[1][dt] = mfma16(ap1, bm, out[1][dt]);
    }

    if (kt < 31){
      const int nxt = cur ^ 1;
      *reinterpret_cast<u16x8*>(&Kst[nxt][kr0*KST + kc0]) = g0;
      if (c1K) *reinterpret_cast<u16x8*>(&Kst[nxt][kr1*KST + kc1]) = g1;
      else     *reinterpret_cast<u16x8*>(&Mst[nxt][md1*MST + mc1]) = g1;
      *reinterpret_cast<u16x8*>(&Mst[nxt][md2*MST + mc2]) = g2;
    }
    __syncthreads();
  }

#pragma unroll
  for (int rt = 0; rt < 2; ++rt)
#pragma unroll
    for (int rg = 0; rg < 4; ++rg){
      float s = ssum[rt][rg];
#pragma unroll
      for (int off = 1; off < 16; off <<= 1) s += __shfl_xor(s, off);
      ssum[rt][rg] = 1.f / s;
    }

#pragma unroll
  for (int dt = 0; dt < 6; ++dt){
    float cvv = cv[(size_t)bh*96 + dt*16 + lm];
#pragma unroll
    for (int rt = 0; rt < 2; ++rt)
#pragma unroll
      for (int rg = 0; rg < 4; ++rg){
        int row = q0 + rt*16 + lh*4 + rg;
        xh[((size_t)bh*1024 + row)*96 + dt*16 + lm] =
            f2bf(out[rt][dt][rg]*ssum[rt][rg] + cvv);
      }
  }
}

// ---------------------------------------------------------------------------
// Projection (R10): out[t][o] = sum_i xh[t][i]*Wpt[o][i] + b_proj[o].
// Block = 128 tokens x 96 outputs; 4 waves x 32 tokens; staged Wpt tile.
// ---------------------------------------------------------------------------
__global__ __launch_bounds__(256, 2) void proj_kernel(
    const unsigned short* __restrict__ xh, const unsigned short* __restrict__ Wpt,
    const float* __restrict__ b_proj, float* __restrict__ out)
{
  constexpr int BST = 40;    // B-tile row stride (u16): 96 x 40
  __shared__ __align__(16) unsigned short Bst[2][96*BST];    // 15360 B

  const int mb = blockIdx.x;        // 0..63 -> 128 tokens
  const int nb = blockIdx.y;        // 0..7  -> 96 outputs
  const int tid = threadIdx.x;
  const int w = tid >> 6, lane = tid & 63, lh = lane >> 4, lm = lane & 15;
  const int t0 = mb*128 + w*32;
  const int o0 = nb*96;

  const int br0 = tid >> 2,          bc0 = (tid & 3)*8;
  const bool has1 = (tid < 128);
  const int br1 = (tid + 256) >> 2,  bc1 = ((tid + 256) & 3)*8;
  const unsigned short* Bsrc = Wpt + (size_t)o0*768;

  f32x4 acc[2][6];
#pragma unroll
  for (int rt = 0; rt < 2; ++rt)
#pragma unroll
    for (int nt = 0; nt < 6; ++nt) acc[rt][nt] = f32x4{0.f, 0.f, 0.f, 0.f};

  const int tok0 = t0 + lm, tok1 = t0 + 16 + lm;
  const int b0 = tok0 >> 10, n0_ = tok0 & 1023;
  const int b1 = tok1 >> 10, n1_ = tok1 & 1023;

  u16x8 g0, g1;
  g0 = *reinterpret_cast<const u16x8*>(Bsrc + (size_t)br0*768 + bc0);
  if (has1) g1 = *reinterpret_cast<const u16x8*>(Bsrc + (size_t)br1*768 + bc1);
  *reinterpret_cast<u16x8*>(&Bst[0][br0*BST + bc0]) = g0;
  if (has1) *reinterpret_cast<u16x8*>(&Bst[0][br1*BST + bc1]) = g1;
  __syncthreads();

  for (int kt = 0; kt < 24; ++kt){
    const int cur = kt & 1;

    if (kt < 23){
      const int ib = (kt+1)*32;
      g0 = *reinterpret_cast<const u16x8*>(Bsrc + (size_t)br0*768 + ib + bc0);
      if (has1) g1 = *reinterpret_cast<const u16x8*>(Bsrc + (size_t)br1*768 + ib + bc1);
    }

    const int h = kt/3, d0 = (kt - h*3)*32 + lh*8;
    bf16x8 a0 = ld8(xh + ((size_t)(b0*8 + h)*1024 + n0_)*96 + d0);
    bf16x8 a1 = ld8(xh + ((size_t)(b1*8 + h)*1024 + n1_)*96 + d0);

    const unsigned short* Bc = &Bst[cur][0];
#pragma unroll
    for (int nt = 0; nt < 6; ++nt){
      bf16x8 bv = ld8(Bc + (nt*16 + lm)*BST + lh*8);
      acc[0][nt] = mfma16(a0, bv, acc[0][nt]);
      acc[1][nt] = mfma16(a1, bv, acc[1][nt]);
    }

    if (kt < 23){
      const int nxt = cur ^ 1;
      *reinterpret_cast<u16x8*>(&Bst[nxt][br0*BST + bc0]) = g0;
      if (has1) *reinterpret_cast<u16x8*>(&Bst[nxt][br1*BST + bc1]) = g1;
    }
    __syncthreads();
  }

#pragma unroll
  for (int nt = 0; nt < 6; ++nt){
    int o = o0 + nt*16 + lm;
    float bias = b_proj[o];
#pragma unroll
    for (int rt = 0; rt < 2; ++rt)
#pragma unroll
      for (int rg = 0; rg < 4; ++rg)
        out[(size_t)(t0 + rt*16 + lh*4 + rg)*768 + o] = acc[rt][nt][rg] + bias;
  }
}

// ---------------------------------------------------------------------------
extern "C" void kernel_launch(void* const* d_in, const int* in_sizes, int n_in,
                              void* d_out, int out_size, void* d_ws, size_t ws_size,
                              hipStream_t stream)
{
  (void)in_sizes; (void)n_in; (void)out_size; (void)ws_size;
  const float* q      = (const float*)d_in[0];
  const float* k      = (const float*)d_in[1];
  const float* v      = (const float*)d_in[2];
  const float* wq     = (const float*)d_in[3];
  const float* wk     = (const float*)d_in[4];
  const float* wv     = (const float*)d_in[5];
  const float* w_re   = (const float*)d_in[6];
  const float* b_re   = (const float*)d_in[7];
  const float* gma    = (const float*)d_in[8];
  const float* beta   = (const float*)d_in[9];
  const float* mean   = (const float*)d_in[10];
  const float* var    = (const float*)d_in[11];
  const float* w_proj = (const float*)d_in[12];
  const float* b_proj = (const float*)d_in[13];
  float* out = (float*)d_out;

  // ws layout (bytes): total ~66.3 MB. vh aliases the xh slot (vh is dead
  // before attn writes xh).
  char* ws = (char*)d_ws;
  unsigned short* qh     = (unsigned short*)(ws + 0);          // 12,582,912
  unsigned short* kh     = (unsigned short*)(ws + 12582912);   // 12,582,912
  unsigned short* vtg    = (unsigned short*)(ws + 25165824);   // 12,582,912
  unsigned short* xh     = (unsigned short*)(ws + 37748736);   // 12,582,912
  unsigned short* vh     = xh;                                 // alias (dead before attn)
  unsigned short* Wre_rm = (unsigned short*)(ws + 50331648);   //  2,097,152
  unsigned short* Wpt    = (unsigned short*)(ws + 52428800);   //  1,179,648
  unsigned short* M2t    = (unsigned short*)(ws + 53608448);   // 12,582,912
  float*          G      = (float*)(ws + 66191360);            //      4,096
  float*          Cc     = (float*)(ws + 66195456);            //      4,096
  float*          CoverG = (float*)(ws + 66199552);            //      4,096
  float*          cv     = (float*)(ws + 66203648);            //     24,576

  prep_kernel<<<dim3(4100), dim3(256), 0, stream>>>(w_re, b_re, gma, beta, mean, var,
                                                    Wre_rm, G, Cc, CoverG);
  wpt_kernel<<<dim3(12, 12), dim3(256), 0, stream>>>(w_proj, Wpt);
  conv_kernel<<<dim3(2048, 3), dim3(256), 0, stream>>>(q, k, v, wq, wk, wv, G, qh, kh, vh);
  vt_kernel<<<dim3(8, 64), dim3(256), 0, stream>>>(vh, vtg);
  cv_kernel<<<dim3(512), dim3(256), 0, stream>>>(vtg, CoverG, cv);
  m2_kernel<<<dim3(512), dim3(256), 0, stream>>>(Wre_rm, vtg, M2t);
  attn_kernel<<<dim3(512), dim3(256), 0, stream>>>(qh, kh, M2t, cv, xh);
  proj_kernel<<<dim3(64, 8), dim3(256), 0, stream>>>(xh, Wpt, b_proj, out);
}

// Round 15
// 143.837 us; speedup vs baseline: 1.2076x; 1.0122x over previous
//
#include <hip/hip_runtime.h>
#include <hip/hip_bf16.h>

// Sizes
// B=8, N=1024, S=16, C=3, H=8, DIM=768, HD=96, SCALE=96^-0.5, BN_EPS=1e-3
//
// Algebraic restructuring (R5): out = BN(P@W_re)@V collapses to
//   out[n][d] = sum_m P[n][m] * M2[m][d] + cv[d]
//   M2[m][d]  = sum_p W_re[m][p] * G[p] * V[p][d]      (12.9 GF, batched bh)
//   cv[d]     = sum_p Cc[p] * V[p][d]
// R15: (a) conv gets __launch_bounds__(256,4) so the allocator can keep the
//      36 loads/token in flight (R14's 44-VGPR build serialized them);
//      (b) cv kernel deleted — vt accumulates per-chunk partials
//      cvpart[chunk][bh][d] from its LDS tile, attn sums the 8 partials.

typedef __attribute__((ext_vector_type(4))) float f32x4;
typedef __bf16 __attribute__((ext_vector_type(8))) bf16x8;
typedef unsigned short u16x8 __attribute__((ext_vector_type(8)));

__device__ __forceinline__ unsigned short f2bf(float x){
  unsigned u = __builtin_bit_cast(unsigned, x);
  u += 0x7fffu + ((u >> 16) & 1u);          // round-to-nearest-even
  return (unsigned short)(u >> 16);
}

__device__ __forceinline__ float bf2f(unsigned short u){
  unsigned v = (unsigned)u << 16;
  return __builtin_bit_cast(float, v);
}

__device__ __forceinline__ f32x4 mfma16(bf16x8 a, bf16x8 b, f32x4 c){
  return __builtin_amdgcn_mfma_f32_16x16x32_bf16(a, b, c, 0, 0, 0);
}

__device__ __forceinline__ bf16x8 ld8(const unsigned short* p){
  return *reinterpret_cast<const bf16x8*>(p);
}

// ---------------------------------------------------------------------------
// Prep: Wre_rm[m][p] = bf16(w_re[m][p]) (coalesced cast);
//       G[p] = gamma*rsqrt(var+eps); Cc=(b_re-mean)*G+beta; CoverG=Cc/G
// ---------------------------------------------------------------------------
__global__ void prep_kernel(const float* __restrict__ w_re, const float* __restrict__ b_re,
                            const float* __restrict__ gma, const float* __restrict__ beta,
                            const float* __restrict__ mean, const float* __restrict__ var,
                            unsigned short* __restrict__ Wre_rm,
                            float* __restrict__ G, float* __restrict__ Cc,
                            float* __restrict__ CoverG)
{
  int idx = blockIdx.x * 256 + threadIdx.x;
  if (idx < 1024*1024){
    Wre_rm[idx] = f2bf(w_re[idx]);
  } else if (idx < 1024*1024 + 1024){
    int p = idx - 1024*1024;
    float g = gma[p] * rsqrtf(var[p] + 1e-3f);
    float cc = (b_re[p] - mean[p]) * g + beta[p];
    G[p] = g;
    Cc[p] = cc;
    CoverG[p] = cc / g;
  }
}

// ---------------------------------------------------------------------------
// Wpt[o][i] = bf16(w_proj[i][o]) via LDS 64x64 tiles (coalesced both sides)
// ---------------------------------------------------------------------------
__global__ __launch_bounds__(256) void wpt_kernel(const float* __restrict__ wp,
                                                  unsigned short* __restrict__ Wpt)
{
  __shared__ float t[64][65];
  const int i0 = blockIdx.x * 64, o0 = blockIdx.y * 64;
  const int r = threadIdx.x >> 6;        // 0..3
  const int c = threadIdx.x & 63;        // 0..63
#pragma unroll
  for (int rep = 0; rep < 16; ++rep){
    int row = rep*4 + r;
    t[row][c] = wp[(size_t)(i0 + row)*768 + o0 + c];
  }
  __syncthreads();
#pragma unroll
  for (int rep = 0; rep < 16; ++rep){
    int orow = rep*4 + r;
    Wpt[(size_t)(o0 + orow)*768 + i0 + c] = f2bf(t[c][orow]);
  }
}

// ---------------------------------------------------------------------------
// Conv 3x3 SAME (R15); 4 tokens/block, pixel-per-thread, NO LDS.
// __launch_bounds__(256,4): 128-reg budget so loads pipeline (R14 fix).
// Taps read directly from global (dwordx3; L1/L2-resident working set).
// Halo: branchless per-thread clamped offsets + 0/1 mask floats.
// Weights SGPR-resident. qh/kh/vh [B,H,N,96]; vh scaled by G[n].
// ---------------------------------------------------------------------------
__global__ __launch_bounds__(256, 4) void conv_kernel(
    const float* __restrict__ q, const float* __restrict__ k,
    const float* __restrict__ v,
    const float* __restrict__ wq, const float* __restrict__ wk,
    const float* __restrict__ wv,
    const float* __restrict__ G,
    unsigned short* __restrict__ qh, unsigned short* __restrict__ kh,
    unsigned short* __restrict__ vh)
{
  const int tb = blockIdx.x;         // 0..2047 (4 tokens each)
  const int which = blockIdx.y;      // 0=q 1=k 2=v
  const float* x = (which == 0) ? q : (which == 1) ? k : v;
  const float* w = (which == 0) ? wq : (which == 1) ? wk : wv;
  unsigned short* dst = (which == 0) ? qh : (which == 1) ? kh : vh;

  // weights -> SGPRs (uniform pointer, compile-time offsets => s_load)
  float wreg[81];
#pragma unroll
  for (int i = 0; i < 81; ++i) wreg[i] = w[i];

  const int tid = threadIdx.x;       // pixel id 0..255
  const int c = tid & 15, r = tid >> 4;

  // per-thread tap masks and clamped offsets (computed once)
  float msk[9];
  int   off[9];
#pragma unroll
  for (int dr = 0; dr < 3; ++dr)
#pragma unroll
    for (int dc = 0; dc < 3; ++dc){
      int rr = r + dr - 1, cc = c + dc - 1;
      bool valid = (rr >= 0) && (rr < 16) && (cc >= 0) && (cc < 16);
      int rc = rr < 0 ? 0 : (rr > 15 ? 15 : rr);
      int cl = cc < 0 ? 0 : (cc > 15 ? 15 : cc);
      msk[dr*3 + dc] = valid ? 1.f : 0.f;
      off[dr*3 + dc] = (rc*16 + cl)*3;
    }

#pragma unroll
  for (int tk = 0; tk < 4; ++tk){
    const float* xt = x + ((size_t)(tb*4 + tk))*768;
    float a0 = 0.f, a1 = 0.f, a2 = 0.f;
#pragma unroll
    for (int j = 0; j < 9; ++j){
      const float* p = xt + off[j];
      float m = msk[j];
      float x0 = p[0]*m, x1 = p[1]*m, x2 = p[2]*m;   // -> global_load_dwordx3
      const int wb = j*9;
      a0 += x0*wreg[wb+0] + x1*wreg[wb+3] + x2*wreg[wb+6];
      a1 += x0*wreg[wb+1] + x1*wreg[wb+4] + x2*wreg[wb+7];
      a2 += x0*wreg[wb+2] + x1*wreg[wb+5] + x2*wreg[wb+8];
    }
    const int token = tb*4 + tk;
    const int b = token >> 10, n = token & 1023;
    const float gs = (which == 2) ? G[n] : 1.f;      // uniform per block -> s_load
    float av[3] = {a0*gs, a1*gs, a2*gs};
#pragma unroll
    for (int co = 0; co < 3; ++co){
      int f = tid*3 + co;                  // head boundary (96) never splits a thread
      int h = f / 96, d = f - h*96;
      dst[((size_t)(b*8 + h)*1024 + n)*96 + d] = f2bf(av[co]);
    }
  }
}

// ---------------------------------------------------------------------------
// Transpose vh[bh][n][96] -> vtg[bh][d][n] via LDS tile, coalesced both sides.
// R15: also accumulates cvpart[chunk][bh][d] = sum_{n in chunk} CoverG[n]*V[d][n]
// from the values already in registers during pass 2 (deterministic partials;
// attn sums the 8 chunks). Grid (8 n-chunks, 64 bh).
// ---------------------------------------------------------------------------
__global__ __launch_bounds__(256) void vt_kernel(const unsigned short* __restrict__ vh,
                                                 const float* __restrict__ CoverG,
                                                 unsigned short* __restrict__ vtg,
                                                 float* __restrict__ cvpart)
{
  __shared__ unsigned short t[96*136];       // row d: stride 136 (272 B, 16B-aligned, odd*16B)
  const int chunk = blockIdx.x;              // 0..7
  const int bh = blockIdx.y;                 // 0..63
  const int n0 = chunk*128;
  const int tid = threadIdx.x;

  const unsigned short* src = vh + ((size_t)bh*1024 + n0)*96;
#pragma unroll
  for (int it = 0; it < 6; ++it){
    int idx = it*256 + tid;                  // 0..1535
    int row = idx / 12, v = idx - row*12;    // row 0..127, v 0..11
    u16x8 xv = *reinterpret_cast<const u16x8*>(src + row*96 + v*8);
#pragma unroll
    for (int j = 0; j < 8; ++j) t[(v*8 + j)*136 + row] = xv[j];
  }
  __syncthreads();

  unsigned short* dstp = vtg + (size_t)bh*96*1024 + n0;
#pragma unroll
  for (int it = 0; it < 6; ++it){
    int idx = it*256 + tid;                  // 0..1535
    int d = idx >> 4, ch = idx & 15;         // d 0..95, ch 0..15
    u16x8 xv = *reinterpret_cast<const u16x8*>(&t[d*136 + ch*8]);
    *reinterpret_cast<u16x8*>(dstp + (size_t)d*1024 + ch*8) = xv;

    // cv partial: this thread holds V[d][n0+ch*8 .. +8)
    float s = 0.f;
#pragma unroll
    for (int j = 0; j < 8; ++j) s += CoverG[n0 + ch*8 + j] * bf2f(xv[j]);
#pragma unroll
    for (int o = 1; o < 16; o <<= 1) s += __shfl_xor(s, o);   // reduce 16-lane group
    if (ch == 0) cvpart[((size_t)chunk*64 + bh)*96 + d] = s;
  }
}

// ---------------------------------------------------------------------------
// M2t[bh][d][m] = sum_p Wre_rm[m][p] * vtg[bh][d][p]   (K = 1024 over p)
// R11: block-staged double-buffered W-tile (128x32) + V-tile (96x32);
// 4 waves x 32 m-rows; 12 MFMA/wave-iter; one barrier/iter.
// ---------------------------------------------------------------------------
__global__ __launch_bounds__(256, 2) void m2_kernel(
    const unsigned short* __restrict__ Wre_rm, const unsigned short* __restrict__ vtg,
    unsigned short* __restrict__ M2t)
{
  constexpr int WST = 40;   // W-tile row stride (u16): 128 x 40
  constexpr int VST = 40;   // V-tile row stride (u16): 96 x 40
  __shared__ __align__(16) unsigned short Wst[2][128*WST];   // 20480 B
  __shared__ __align__(16) unsigned short Vst[2][96*VST];    // 15360 B -> 35840 B

  const int id = blockIdx.x;             // 0..511
  const int xcd = id & 7, slot = id >> 3;
  const int mtile = slot & 7;            // 0..7
  const int bh = xcd + ((slot >> 3) << 3);
  const int tid = threadIdx.x;
  const int w = tid >> 6, lane = tid & 63, lh = lane >> 4, lm = lane & 15;
  const int m0 = mtile*128;              // block's m-base
  const int mw = w*32;                   // wave's m offset in tile

  const unsigned short* vb = vtg + (size_t)bh * 96 * 1024;
  const unsigned short* Wb = Wre_rm + (size_t)m0 * 1024;

  const int cr = tid >> 2, cc0 = (tid & 3)*8;
  const bool has3 = (tid < 128);

  f32x4 acc[2][6];
#pragma unroll
  for (int rt = 0; rt < 2; ++rt)
#pragma unroll
    for (int dt = 0; dt < 6; ++dt)
      acc[rt][dt] = f32x4{0.f, 0.f, 0.f, 0.f};

  // --- prologue: stage p-tile 0 into buffer 0 ---
  u16x8 g0, g1, g2, g3;
  g0 = *reinterpret_cast<const u16x8*>(Wb + (size_t)cr*1024 + cc0);
  g1 = *reinterpret_cast<const u16x8*>(Wb + (size_t)(64 + cr)*1024 + cc0);
  g2 = *reinterpret_cast<const u16x8*>(vb + (size_t)cr*1024 + cc0);
  if (has3) g3 = *reinterpret_cast<const u16x8*>(vb + (size_t)(64 + cr)*1024 + cc0);
  *reinterpret_cast<u16x8*>(&Wst[0][cr*WST + cc0]) = g0;
  *reinterpret_cast<u16x8*>(&Wst[0][(64 + cr)*WST + cc0]) = g1;
  *reinterpret_cast<u16x8*>(&Vst[0][cr*VST + cc0]) = g2;
  if (has3) *reinterpret_cast<u16x8*>(&Vst[0][(64 + cr)*VST + cc0]) = g3;
  __syncthreads();

  for (int ks = 0; ks < 32; ++ks){
    const int cur = ks & 1;

    if (ks < 31){
      const int p0 = (ks+1)*32;
      g0 = *reinterpret_cast<const u16x8*>(Wb + (size_t)cr*1024 + p0 + cc0);
      g1 = *reinterpret_cast<const u16x8*>(Wb + (size_t)(64 + cr)*1024 + p0 + cc0);
      g2 = *reinterpret_cast<const u16x8*>(vb + (size_t)cr*1024 + p0 + cc0);
      if (has3) g3 = *reinterpret_cast<const u16x8*>(vb + (size_t)(64 + cr)*1024 + p0 + cc0);
    }

    const unsigned short* Wc = &Wst[cur][0];
    const unsigned short* Vc = &Vst[cur][0];
    bf16x8 aW0 = ld8(Wc + (mw + lm)*WST + lh*8);
    bf16x8 aW1 = ld8(Wc + (mw + 16 + lm)*WST + lh*8);
#pragma unroll
    for (int dt = 0; dt < 6; ++dt){
      bf16x8 bV = ld8(Vc + (dt*16 + lm)*VST + lh*8);
      acc[0][dt] = mfma16(aW0, bV, acc[0][dt]);
      acc[1][dt] = mfma16(aW1, bV, acc[1][dt]);
    }

    if (ks < 31){
      const int nxt = cur ^ 1;
      *reinterpret_cast<u16x8*>(&Wst[nxt][cr*WST + cc0]) = g0;
      *reinterpret_cast<u16x8*>(&Wst[nxt][(64 + cr)*WST + cc0]) = g1;
      *reinterpret_cast<u16x8*>(&Vst[nxt][cr*VST + cc0]) = g2;
      if (has3) *reinterpret_cast<u16x8*>(&Vst[nxt][(64 + cr)*VST + cc0]) = g3;
    }
    __syncthreads();
  }

#pragma unroll
  for (int rt = 0; rt < 2; ++rt)
#pragma unroll
    for (int dt = 0; dt < 6; ++dt)
#pragma unroll
      for (int rg = 0; rg < 4; ++rg){
        int m = m0 + mw + rt*16 + lh*4 + rg;
        int d = dt*16 + lm;
        M2t[((size_t)bh*96 + d)*1024 + m] = f2bf(acc[rt][dt][rg]);
      }
}

// ---------------------------------------------------------------------------
// Fused attention (R9): block-staged K/M2 tiles, double-buffered.
// 256 thr = 4 waves; block owns 128 q-rows of one bh; wave w: 32 rows.
// R15: cv read as sum of 8 per-chunk partials (deterministic).
// ---------------------------------------------------------------------------
__global__ __launch_bounds__(256, 2) void attn_kernel(
    const unsigned short* __restrict__ qh, const unsigned short* __restrict__ kh,
    const unsigned short* __restrict__ M2t, const float* __restrict__ cvpart,
    unsigned short* __restrict__ xh)
{
  constexpr int KST = 104;   // K-tile row stride (u16): 32 x 104
  constexpr int MST = 40;    // M-tile row stride (u16): 96 x 40
  constexpr int PST = 40;    // P stage row stride (u16): 32 x 40 per wave
  __shared__ __align__(16) unsigned short Kst[2][32*KST];    // 13312 B
  __shared__ __align__(16) unsigned short Mst[2][96*MST];    // 15360 B
  __shared__ __align__(16) unsigned short Pst[2][4][32*PST]; // 20480 B -> total 49152 B

  const int id = blockIdx.x;             // 0..511
  const int xcd = id & 7, slot = id >> 3;
  const int chunk = slot & 7;            // 128-row chunk
  const int bh = xcd + ((slot >> 3) << 3);
  const int tid = threadIdx.x;
  const int w = tid >> 6;                // 0..3
  const int lane = tid & 63;
  const int lh = lane >> 4;              // 0..3
  const int lm = lane & 15;              // 0..15
  const int q0 = chunk*128 + w*32;       // this wave's 32 q-rows

  const unsigned short* Qb = qh + (size_t)bh * 1024 * 96;
  const unsigned short* Kb = kh + (size_t)bh * 1024 * 96;
  const unsigned short* Mb = M2t + (size_t)bh * 96 * 1024;

  const int kr0 = tid/12,  kc0 = (tid%12)*8;
  const bool c1K = (tid < 128);
  const int t1 = tid + 256;
  const int kr1 = c1K ? t1/12 : 0,  kc1 = c1K ? (t1%12)*8 : 0;
  const int md1 = c1K ? 0 : (tid-128)>>2, mc1 = c1K ? 0 : ((tid-128)&3)*8;
  const int md2 = (tid+128)>>2, mc2 = ((tid+128)&3)*8;

  bf16x8 aq[2][3];
#pragma unroll
  for (int rt = 0; rt < 2; ++rt)
#pragma unroll
    for (int kq = 0; kq < 3; ++kq)
      aq[rt][kq] = ld8(Qb + (size_t)(q0 + rt*16 + lm)*96 + kq*32 + lh*8);

  f32x4 out[2][6];
#pragma unroll
  for (int rt = 0; rt < 2; ++rt)
#pragma unroll
    for (int dt = 0; dt < 6; ++dt) out[rt][dt] = f32x4{0.f, 0.f, 0.f, 0.f};
  f32x4 ssum[2] = {f32x4{0.f,0.f,0.f,0.f}, f32x4{0.f,0.f,0.f,0.f}};

  const float SCALE = 0.10206207261596577f;

  u16x8 g0, g1, g2;
  {
    g0 = *reinterpret_cast<const u16x8*>(Kb + (size_t)kr0*96 + kc0);
    g1 = c1K ? *reinterpret_cast<const u16x8*>(Kb + (size_t)kr1*96 + kc1)
             : *reinterpret_cast<const u16x8*>(Mb + (size_t)md1*1024 + mc1);
    g2 = *reinterpret_cast<const u16x8*>(Mb + (size_t)md2*1024 + mc2);
    *reinterpret_cast<u16x8*>(&Kst[0][kr0*KST + kc0]) = g0;
    if (c1K) *reinterpret_cast<u16x8*>(&Kst[0][kr1*KST + kc1]) = g1;
    else     *reinterpret_cast<u16x8*>(&Mst[0][md1*MST + mc1]) = g1;
    *reinterpret_cast<u16x8*>(&Mst[0][md2*MST + mc2]) = g2;
  }
  __syncthreads();

  for (int kt = 0; kt < 32; ++kt){
    const int cur = kt & 1;

    if (kt < 31){
      const int kb = (kt+1)*32;
      g0 = *reinterpret_cast<const u16x8*>(Kb + (size_t)(kb + kr0)*96 + kc0);
      g1 = c1K ? *reinterpret_cast<const u16x8*>(Kb + (size_t)(kb + kr1)*96 + kc1)
               : *reinterpret_cast<const u16x8*>(Mb + (size_t)md1*1024 + kb + mc1);
      g2 = *reinterpret_cast<const u16x8*>(Mb + (size_t)md2*1024 + kb + mc2);
    }

    const unsigned short* Kc = &Kst[cur][0];
    f32x4 sacc[2][2];
    sacc[0][0] = f32x4{0.f,0.f,0.f,0.f}; sacc[0][1] = f32x4{0.f,0.f,0.f,0.f};
    sacc[1][0] = f32x4{0.f,0.f,0.f,0.f}; sacc[1][1] = f32x4{0.f,0.f,0.f,0.f};
#pragma unroll
    for (int kq = 0; kq < 3; ++kq){
      bf16x8 bk0 = ld8(Kc + lm*KST        + kq*32 + lh*8);
      bf16x8 bk1 = ld8(Kc + (16 + lm)*KST + kq*32 + lh*8);
      sacc[0][0] = mfma16(aq[0][kq], bk0, sacc[0][0]);
      sacc[0][1] = mfma16(aq[0][kq], bk1, sacc[0][1]);
      sacc[1][0] = mfma16(aq[1][kq], bk0, sacc[1][0]);
      sacc[1][1] = mfma16(aq[1][kq], bk1, sacc[1][1]);
    }

    unsigned short* Pc = &Pst[cur][w][0];
#pragma unroll
    for (int rt = 0; rt < 2; ++rt)
#pragma unroll
      for (int nt = 0; nt < 2; ++nt)
#pragma unroll
        for (int rg = 0; rg < 4; ++rg){
          float e = __expf(sacc[rt][nt][rg] * SCALE);
          ssum[rt][rg] += e;
          Pc[(rt*16 + lh*4 + rg)*PST + nt*16 + lm] = f2bf(e);
        }

    bf16x8 ap0 = ld8(Pc + lm*PST        + lh*8);
    bf16x8 ap1 = ld8(Pc + (16 + lm)*PST + lh*8);

    const unsigned short* Mc = &Mst[cur][0];
#pragma unroll
    for (int dt = 0; dt < 6; ++dt){
      bf16x8 bm = ld8(Mc + (dt*16 + lm)*MST + lh*8);
      out[0][dt] = mfma16(ap0, bm, out[0][dt]);
      out[1][dt] = mfma16(ap1, bm, out[1][dt]);
    }

    if (kt < 31){
      const int nxt = cur ^ 1;
      *reinterpret_cast<u16x8*>(&Kst[nxt][kr0*KST + kc0]) = g0;
      if (c1K) *reinterpret_cast<u16x8*>(&Kst[nxt][kr1*KST + kc1]) = g1;
      else     *reinterpret_cast<u16x8*>(&Mst[nxt][md1*MST + mc1]) = g1;
      *reinterpret_cast<u16x8*>(&Mst[nxt][md2*MST + mc2]) = g2;
    }
    __syncthreads();
  }

#pragma unroll
  for (int rt = 0; rt < 2; ++rt)
#pragma unroll
    for (int rg = 0; rg < 4; ++rg){
      float s = ssum[rt][rg];
#pragma unroll
      for (int off = 1; off < 16; off <<= 1) s += __shfl_xor(s, off);
      ssum[rt][rg] = 1.f / s;
    }

#pragma unroll
  for (int dt = 0; dt < 6; ++dt){
    float cvv = 0.f;
#pragma unroll
    for (int ch = 0; ch < 8; ++ch)
      cvv += cvpart[((size_t)ch*64 + bh)*96 + dt*16 + lm];
#pragma unroll
    for (int rt = 0; rt < 2; ++rt)
#pragma unroll
      for (int rg = 0; rg < 4; ++rg){
        int row = q0 + rt*16 + lh*4 + rg;
        xh[((size_t)bh*1024 + row)*96 + dt*16 + lm] =
            f2bf(out[rt][dt][rg]*ssum[rt][rg] + cvv);
      }
  }
}

// ---------------------------------------------------------------------------
// Projection (R10): out[t][o] = sum_i xh[t][i]*Wpt[o][i] + b_proj[o].
// Block = 128 tokens x 96 outputs; 4 waves x 32 tokens; staged Wpt tile.
// ---------------------------------------------------------------------------
__global__ __launch_bounds__(256, 2) void proj_kernel(
    const unsigned short* __restrict__ xh, const unsigned short* __restrict__ Wpt,
    const float* __restrict__ b_proj, float* __restrict__ out)
{
  constexpr int BST = 40;    // B-tile row stride (u16): 96 x 40
  __shared__ __align__(16) unsigned short Bst[2][96*BST];    // 15360 B

  const int mb = blockIdx.x;        // 0..63 -> 128 tokens
  const int nb = blockIdx.y;        // 0..7  -> 96 outputs
  const int tid = threadIdx.x;
  const int w = tid >> 6, lane = tid & 63, lh = lane >> 4, lm = lane & 15;
  const int t0 = mb*128 + w*32;
  const int o0 = nb*96;

  const int br0 = tid >> 2,          bc0 = (tid & 3)*8;
  const bool has1 = (tid < 128);
  const int br1 = (tid + 256) >> 2,  bc1 = ((tid + 256) & 3)*8;
  const unsigned short* Bsrc = Wpt + (size_t)o0*768;

  f32x4 acc[2][6];
#pragma unroll
  for (int rt = 0; rt < 2; ++rt)
#pragma unroll
    for (int nt = 0; nt < 6; ++nt) acc[rt][nt] = f32x4{0.f, 0.f, 0.f, 0.f};

  const int tok0 = t0 + lm, tok1 = t0 + 16 + lm;
  const int b0 = tok0 >> 10, n0_ = tok0 & 1023;
  const int b1 = tok1 >> 10, n1_ = tok1 & 1023;

  u16x8 g0, g1;
  g0 = *reinterpret_cast<const u16x8*>(Bsrc + (size_t)br0*768 + bc0);
  if (has1) g1 = *reinterpret_cast<const u16x8*>(Bsrc + (size_t)br1*768 + bc1);
  *reinterpret_cast<u16x8*>(&Bst[0][br0*BST + bc0]) = g0;
  if (has1) *reinterpret_cast<u16x8*>(&Bst[0][br1*BST + bc1]) = g1;
  __syncthreads();

  for (int kt = 0; kt < 24; ++kt){
    const int cur = kt & 1;

    if (kt < 23){
      const int ib = (kt+1)*32;
      g0 = *reinterpret_cast<const u16x8*>(Bsrc + (size_t)br0*768 + ib + bc0);
      if (has1) g1 = *reinterpret_cast<const u16x8*>(Bsrc + (size_t)br1*768 + ib + bc1);
    }

    const int h = kt/3, d0 = (kt - h*3)*32 + lh*8;
    bf16x8 a0 = ld8(xh + ((size_t)(b0*8 + h)*1024 + n0_)*96 + d0);
    bf16x8 a1 = ld8(xh + ((size_t)(b1*8 + h)*1024 + n1_)*96 + d0);

    const unsigned short* Bc = &Bst[cur][0];
#pragma unroll
    for (int nt = 0; nt < 6; ++nt){
      bf16x8 bv = ld8(Bc + (nt*16 + lm)*BST + lh*8);
      acc[0][nt] = mfma16(a0, bv, acc[0][nt]);
      acc[1][nt] = mfma16(a1, bv, acc[1][nt]);
    }

    if (kt < 23){
      const int nxt = cur ^ 1;
      *reinterpret_cast<u16x8*>(&Bst[nxt][br0*BST + bc0]) = g0;
      if (has1) *reinterpret_cast<u16x8*>(&Bst[nxt][br1*BST + bc1]) = g1;
    }
    __syncthreads();
  }

#pragma unroll
  for (int nt = 0; nt < 6; ++nt){
    int o = o0 + nt*16 + lm;
    float bias = b_proj[o];
#pragma unroll
    for (int rt = 0; rt < 2; ++rt)
#pragma unroll
      for (int rg = 0; rg < 4; ++rg)
        out[(size_t)(t0 + rt*16 + lh*4 + rg)*768 + o] = acc[rt][nt][rg] + bias;
  }
}

// ---------------------------------------------------------------------------
extern "C" void kernel_launch(void* const* d_in, const int* in_sizes, int n_in,
                              void* d_out, int out_size, void* d_ws, size_t ws_size,
                              hipStream_t stream)
{
  (void)in_sizes; (void)n_in; (void)out_size; (void)ws_size;
  const float* q      = (const float*)d_in[0];
  const float* k      = (const float*)d_in[1];
  const float* v      = (const float*)d_in[2];
  const float* wq     = (const float*)d_in[3];
  const float* wk     = (const float*)d_in[4];
  const float* wv     = (const float*)d_in[5];
  const float* w_re   = (const float*)d_in[6];
  const float* b_re   = (const float*)d_in[7];
  const float* gma    = (const float*)d_in[8];
  const float* beta   = (const float*)d_in[9];
  const float* mean   = (const float*)d_in[10];
  const float* var    = (const float*)d_in[11];
  const float* w_proj = (const float*)d_in[12];
  const float* b_proj = (const float*)d_in[13];
  float* out = (float*)d_out;

  // ws layout (bytes): total ~66.5 MB. vh aliases the xh slot (vh is dead
  // before attn writes xh).
  char* ws = (char*)d_ws;
  unsigned short* qh     = (unsigned short*)(ws + 0);          // 12,582,912
  unsigned short* kh     = (unsigned short*)(ws + 12582912);   // 12,582,912
  unsigned short* vtg    = (unsigned short*)(ws + 25165824);   // 12,582,912
  unsigned short* xh     = (unsigned short*)(ws + 37748736);   // 12,582,912
  unsigned short* vh     = xh;                                 // alias (dead before attn)
  unsigned short* Wre_rm = (unsigned short*)(ws + 50331648);   //  2,097,152
  unsigned short* Wpt    = (unsigned short*)(ws + 52428800);   //  1,179,648
  unsigned short* M2t    = (unsigned short*)(ws + 53608448);   // 12,582,912
  float*          G      = (float*)(ws + 66191360);            //      4,096
  float*          Cc     = (float*)(ws + 66195456);            //      4,096
  float*          CoverG = (float*)(ws + 66199552);            //      4,096
  float*          cvpart = (float*)(ws + 66203648);            //    196,608

  prep_kernel<<<dim3(4100), dim3(256), 0, stream>>>(w_re, b_re, gma, beta, mean, var,
                                                    Wre_rm, G, Cc, CoverG);
  wpt_kernel<<<dim3(12, 12), dim3(256), 0, stream>>>(w_proj, Wpt);
  conv_kernel<<<dim3(2048, 3), dim3(256), 0, stream>>>(q, k, v, wq, wk, wv, G, qh, kh, vh);
  vt_kernel<<<dim3(8, 64), dim3(256), 0, stream>>>(vh, CoverG, vtg, cvpart);
  m2_kernel<<<dim3(512), dim3(256), 0, stream>>>(Wre_rm, vtg, M2t);
  attn_kernel<<<dim3(512), dim3(256), 0, stream>>>(qh, kh, M2t, cvpart, xh);
  proj_kernel<<<dim3(64, 8), dim3(256), 0, stream>>>(xh, Wpt, b_proj, out);
}